// Round 9
// baseline (469.507 us; speedup 1.0000x reference)
//
#include <hip/hip_runtime.h>
#include <math.h>

// Problem constants
#define CB 2
#define CS 512
#define CD 1024
#define CH 16
#define CHD 64
#define CF 4096
#define CE 8
#define CK 2
#define CT (CB*CS)      // 1024 tokens
#define CBH (CB*CH)     // 32 (batch*heads)
#define CEPS 1e-6f
#define QKVP 3072       // packed q|k|v row pitch
#define MAXROWS 3072    // 2048 + 8*127 padded to 128
#define MAXTILES (MAXROWS/128)

typedef __attribute__((ext_vector_type(8))) short bf16x8;
typedef __attribute__((ext_vector_type(4))) float f32x4;

__device__ __forceinline__ short f2bf(float f) {
  unsigned u = __float_as_uint(f);
  unsigned r = (u + 0x7FFF + ((u >> 16) & 1)) >> 16;
  return (short)r;
}
__device__ __forceinline__ float bf2f(short h) {
  return __uint_as_float(((unsigned)(unsigned short)h) << 16);
}

__device__ __forceinline__ void gload_lds16(const void* g, void* l) {
  __builtin_amdgcn_global_load_lds(
      (const __attribute__((address_space(1))) unsigned int*)g,
      (__attribute__((address_space(3))) unsigned int*)l, 16, 0, 0);
}

// ---------------------------------------------------------------------------
// RMSNorm. MODE 0: fp32 out (outA). MODE 2: hi/lo bf16 planes (outA=hi, outB=lo)
template <int MODE>
__global__ __launch_bounds__(256) void rmsnorm_kernel(
    const float* __restrict__ x, const float* __restrict__ w,
    void* __restrict__ outA, void* __restrict__ outB) {
  int t = blockIdx.x;
  int tid = threadIdx.x;
  float4 xv = ((const float4*)(x + (size_t)t * CD))[tid];
  float ss = xv.x*xv.x + xv.y*xv.y + xv.z*xv.z + xv.w*xv.w;
  for (int off = 32; off > 0; off >>= 1) ss += __shfl_down(ss, off);
  __shared__ float red[4];
  __shared__ float s_scale;
  int lane = tid & 63, wid = tid >> 6;
  if (lane == 0) red[wid] = ss;
  __syncthreads();
  if (tid == 0) {
    float tot = red[0] + red[1] + red[2] + red[3];
    s_scale = rsqrtf(tot / (float)CD + CEPS);
  }
  __syncthreads();
  float sc = s_scale;
  float4 wv = ((const float4*)w)[tid];
  float o[4] = {xv.x * sc * wv.x, xv.y * sc * wv.y,
                xv.z * sc * wv.z, xv.w * sc * wv.w};
  if (MODE == 0) {
    ((float4*)((float*)outA + (size_t)t * CD))[tid] =
        make_float4(o[0], o[1], o[2], o[3]);
  } else {
    short4 hi, lo;
    short* hp = (short*)&hi; short* lp = (short*)&lo;
#pragma unroll
    for (int i = 0; i < 4; ++i) {
      short h = f2bf(o[i]);
      hp[i] = h;
      lp[i] = f2bf(o[i] - bf2f(h));
    }
    ((short4*)((short*)outA + (size_t)t * CD))[tid] = hi;
    ((short4*)((short*)outB + (size_t)t * CD))[tid] = lo;
  }
}

// ---------------------------------------------------------------------------
// Tiled transpose+convert, 64x64 tile, 16B short8 stores (8x payload vs 2B):
// W[e][Kd][Nd] f32 -> Wth[e][Nd][Kd] bf16 (+ optional lo plane).
__global__ __launch_bounds__(256) void transpose_convert_kernel(
    const float* __restrict__ W, short* __restrict__ Wth,
    short* __restrict__ Wtl, int Kd, int Nd) {
  int e = blockIdx.z;
  const float* Wb = W + (size_t)e * Kd * Nd;
  size_t obase = (size_t)e * Kd * Nd;
  int n0 = blockIdx.x * 64, k0 = blockIdx.y * 64;
  __shared__ float t[64][65];
  int tid = threadIdx.x;
#pragma unroll
  for (int i = 0; i < 4; ++i) {
    int idx = i * 256 + tid;
    int r = idx >> 4, c4 = (idx & 15) * 4;
    float4 v = *(const float4*)(Wb + (size_t)(k0 + r) * Nd + n0 + c4);
    t[r][c4] = v.x; t[r][c4 + 1] = v.y; t[r][c4 + 2] = v.z; t[r][c4 + 3] = v.w;
  }
  __syncthreads();
  int n = tid >> 2, k16 = (tid & 3) * 16;
  short th[16], tl[16];
#pragma unroll
  for (int j = 0; j < 16; ++j) {
    float v = t[k16 + j][n];
    short hi = f2bf(v);
    th[j] = hi;
    tl[j] = f2bf(v - bf2f(hi));
  }
  size_t oo = obase + (size_t)(n0 + n) * Kd + k0 + k16;
  ((int4*)(Wth + oo))[0] = ((int4*)th)[0];
  ((int4*)(Wth + oo + 8))[0] = ((int4*)th)[1];
  if (Wtl) {
    ((int4*)(Wtl + oo))[0] = ((int4*)tl)[0];
    ((int4*)(Wtl + oo + 8))[0] = ((int4*)tl)[1];
  }
}

__global__ void pack_bias_kernel(const float* __restrict__ bq,
                                 const float* __restrict__ bk,
                                 const float* __restrict__ bv,
                                 float* __restrict__ out) {
  int i = blockIdx.x * 256 + threadIdx.x;
  if (i < QKVP)
    out[i] = (i < 1024) ? bq[i] : (i < 2048 ? bk[i - 1024] : bv[i - 2048]);
}

// ---------------------------------------------------------------------------
// MoE grouped GEMM (unchanged from round 8): BM=128, BN=256, BK=64, 8 waves.
template <int SILU, int OUTBF>
__global__ __launch_bounds__(512) void moe_gemm_kernel(
    const short* __restrict__ A, const short* __restrict__ Bt,
    const float* __restrict__ bias, void* __restrict__ Cout,
    float* __restrict__ part, int partM, int N, int K,
    const int* __restrict__ tile_e, const int* __restrict__ total_rows) {
  __shared__ __align__(16) short A0[128 * 64], A1[128 * 64];
  __shared__ __align__(16) short B0[256 * 64], B1[256 * 64];
  int tid = threadIdx.x;
  int m0 = blockIdx.y * 128, n0 = blockIdx.x * 256;
  if (m0 >= *total_rows) return;
  int e = tile_e[blockIdx.y];
  const short* Bb = Bt + (size_t)e * N * K;
  const float* biasb = bias ? bias + (size_t)e * N : nullptr;
  int kz = blockIdx.z;
  int kchunk = K / gridDim.z;
  int kbeg = kz * kchunk;
  int nsteps = kchunk >> 6;
  int lane = tid & 63, w = tid >> 6;
  int wr = w >> 2, wc = w & 3;
  int l15 = lane & 15, l4 = lane >> 4;
  f32x4 acc[4][4] = {};

#define STAGE(AS_, BS_, KK)                                                   \
  {                                                                           \
    _Pragma("unroll") for (int i = 0; i < 2; ++i) {                           \
      int c = i * 512 + tid;                                                  \
      int r = c >> 3, gs = c & 7;                                             \
      int g = gs ^ (r & 7);                                                   \
      gload_lds16(A + (size_t)(m0 + r) * K + (KK) + g * 8, &AS_[c * 8]);      \
    }                                                                         \
    _Pragma("unroll") for (int i = 0; i < 4; ++i) {                           \
      int c = i * 512 + tid;                                                  \
      int r = c >> 3, gs = c & 7;                                             \
      int g = gs ^ (r & 7);                                                   \
      gload_lds16(Bb + (size_t)(n0 + r) * K + (KK) + g * 8, &BS_[c * 8]);     \
    }                                                                         \
  }

#define COMPUTE(AS_, BS_)                                                     \
  {                                                                           \
    _Pragma("unroll") for (int ks = 0; ks < 2; ++ks) {                        \
      bf16x8 a[4], b[4];                                                      \
      _Pragma("unroll") for (int m = 0; m < 4; ++m) {                         \
        int row = wr * 64 + m * 16 + l15;                                     \
        int slot = (ks * 4 + l4) ^ (row & 7);                                 \
        a[m] = *(const bf16x8*)&AS_[(row * 8 + slot) * 8];                    \
      }                                                                       \
      _Pragma("unroll") for (int n = 0; n < 4; ++n) {                         \
        int row = wc * 64 + n * 16 + l15;                                     \
        int slot = (ks * 4 + l4) ^ (row & 7);                                 \
        b[n] = *(const bf16x8*)&BS_[(row * 8 + slot) * 8];                    \
      }                                                                       \
      _Pragma("unroll") for (int m = 0; m < 4; ++m)                           \
      _Pragma("unroll") for (int n = 0; n < 4; ++n)                           \
        acc[m][n] = __builtin_amdgcn_mfma_f32_16x16x32_bf16(a[m], b[n],       \
                                                            acc[m][n], 0, 0, 0); \
    }                                                                         \
  }

  STAGE(A0, B0, kbeg);
  __syncthreads();
  for (int s = 0; s < nsteps; s += 2) {
    int k0 = kbeg + (s << 6);
    bool has1 = (s + 1 < nsteps), has2 = (s + 2 < nsteps);
    if (has1) STAGE(A1, B1, k0 + 64);
    COMPUTE(A0, B0);
    __syncthreads();
    if (has1) {
      if (has2) STAGE(A0, B0, k0 + 128);
      COMPUTE(A1, B1);
      __syncthreads();
    }
  }
#undef STAGE
#undef COMPUTE

  if (gridDim.z > 1) {
#pragma unroll
    for (int m = 0; m < 4; ++m) {
      int row = m0 + wr * 64 + m * 16 + l4 * 4;
#pragma unroll
      for (int n = 0; n < 4; ++n) {
        int col = n0 + wc * 64 + n * 16 + l15;
#pragma unroll
        for (int q = 0; q < 4; ++q)
          part[((size_t)kz * partM + row + q) * N + col] = acc[m][n][q];
      }
    }
    return;
  }
  float* outf = (float*)Cout;
  short* outb = (short*)Cout;
#pragma unroll
  for (int m = 0; m < 4; ++m) {
    int row = m0 + wr * 64 + m * 16 + l4 * 4;
#pragma unroll
    for (int n = 0; n < 4; ++n) {
      int col = n0 + wc * 64 + n * 16 + l15;
      float bv = biasb[col];
#pragma unroll
      for (int q = 0; q < 4; ++q) {
        float v = acc[m][n][q] + bv;
        if (SILU) v = v / (1.f + __expf(-v));
        if (OUTBF) outb[(size_t)(row + q) * N + col] = f2bf(v);
        else outf[(size_t)(row + q) * N + col] = v;
      }
    }
  }
}

// ---------------------------------------------------------------------------
// Attention MFMA GEMM (unchanged): 128x128, BK=32, 4 waves, hi/lo reg-staged.
template <int LO>
__global__ __launch_bounds__(256) void mfma_gemm_kernel(
    const short* __restrict__ Ah, const short* __restrict__ Al,
    const short* __restrict__ Bh, const short* __restrict__ Bl,
    float* __restrict__ part, int partM, int N, int K) {
  __shared__ short As0[4096], Bs0[4096], As1[4096], Bs1[4096];
  __shared__ short Als0[LO ? 4096 : 64], Bls0[LO ? 4096 : 64];
  __shared__ short Als1[LO ? 4096 : 64], Bls1[LO ? 4096 : 64];
  int tid = threadIdx.x;
  int m0 = blockIdx.y * 128, n0 = blockIdx.x * 128;
  int kz = blockIdx.z;
  int kchunk = K / gridDim.z;
  int kbeg = kz * kchunk;
  int nsteps = kchunk >> 5;
  int lane = tid & 63, w = tid >> 6;
  int wr = w >> 1, wc = w & 1;
  int l15 = lane & 15, l4 = lane >> 4;
  int xorl = (l15 & 3) ^ ((l15 >> 2) & 3);
  f32x4 acc[4][4] = {};
  bf16x8 vA0[2], vB0[2], vAl0[2], vBl0[2];
  bf16x8 vA1[2], vB1[2], vAl1[2], vBl1[2];

#define LOAD_SET(VA, VB, VAL, VBL, KK)                                        \
  {                                                                           \
    _Pragma("unroll") for (int ic = 0; ic < 2; ++ic) {                        \
      int c = ic * 256 + tid;                                                 \
      int r = c >> 2, g = c & 3;                                              \
      size_t ao = (size_t)(m0 + r) * K + (KK) + g * 8;                        \
      size_t bo = (size_t)(n0 + r) * K + (KK) + g * 8;                        \
      VA[ic] = *(const bf16x8*)(Ah + ao);                                     \
      VB[ic] = *(const bf16x8*)(Bh + bo);                                     \
      if (LO) {                                                               \
        VAL[ic] = *(const bf16x8*)(Al + ao);                                  \
        VBL[ic] = *(const bf16x8*)(Bl + bo);                                  \
      }                                                                       \
    }                                                                         \
  }

#define WRITE_SET(AS_, BS_, ALS_, BLS_, VA, VB, VAL, VBL)                     \
  {                                                                           \
    _Pragma("unroll") for (int ic = 0; ic < 2; ++ic) {                        \
      int c = ic * 256 + tid;                                                 \
      int r = c >> 2, g = c & 3;                                              \
      int ch = (r * 4 + (g ^ (r & 3) ^ ((r >> 2) & 3))) * 8;                  \
      *(bf16x8*)&AS_[ch] = VA[ic];                                            \
      *(bf16x8*)&BS_[ch] = VB[ic];                                            \
      if (LO) {                                                               \
        *(bf16x8*)&ALS_[ch] = VAL[ic];                                        \
        *(bf16x8*)&BLS_[ch] = VBL[ic];                                        \
      }                                                                       \
    }                                                                         \
  }

#define COMPUTE_SET(AS_, BS_, ALS_, BLS_)                                     \
  {                                                                           \
    bf16x8 ah[4], al[4];                                                      \
    _Pragma("unroll") for (int m = 0; m < 4; ++m) {                           \
      int row = wr * 64 + m * 16 + l15;                                       \
      int idx = (row * 4 + (l4 ^ xorl)) * 8;                                  \
      ah[m] = *(const bf16x8*)&AS_[idx];                                      \
      if (LO) al[m] = *(const bf16x8*)&ALS_[idx];                             \
    }                                                                         \
    _Pragma("unroll") for (int n = 0; n < 4; ++n) {                           \
      int row = wc * 64 + n * 16 + l15;                                       \
      int idx = (row * 4 + (l4 ^ xorl)) * 8;                                  \
      bf16x8 bhn = *(const bf16x8*)&BS_[idx];                                 \
      bf16x8 bln;                                                             \
      if (LO) bln = *(const bf16x8*)&BLS_[idx];                               \
      _Pragma("unroll") for (int m = 0; m < 4; ++m) {                         \
        acc[m][n] = __builtin_amdgcn_mfma_f32_16x16x32_bf16(ah[m], bhn,       \
                                                            acc[m][n], 0, 0, 0); \
        if (LO) {                                                             \
          acc[m][n] = __builtin_amdgcn_mfma_f32_16x16x32_bf16(al[m], bhn,     \
                                                              acc[m][n], 0, 0, 0); \
          acc[m][n] = __builtin_amdgcn_mfma_f32_16x16x32_bf16(ah[m], bln,     \
                                                              acc[m][n], 0, 0, 0); \
        }                                                                     \
      }                                                                       \
    }                                                                         \
  }

  LOAD_SET(vA0, vB0, vAl0, vBl0, kbeg);
  WRITE_SET(As0, Bs0, Als0, Bls0, vA0, vB0, vAl0, vBl0);
  __syncthreads();
  for (int s = 0; s < nsteps; s += 2) {
    int k0 = kbeg + (s << 5);
    bool has1 = (s + 1 < nsteps), has2 = (s + 2 < nsteps);
    if (has1) LOAD_SET(vA1, vB1, vAl1, vBl1, k0 + 32);
    COMPUTE_SET(As0, Bs0, Als0, Bls0);
    if (has1) WRITE_SET(As1, Bs1, Als1, Bls1, vA1, vB1, vAl1, vBl1);
    __syncthreads();
    if (has1) {
      if (has2) LOAD_SET(vA0, vB0, vAl0, vBl0, k0 + 64);
      COMPUTE_SET(As1, Bs1, Als1, Bls1);
      if (has2) WRITE_SET(As0, Bs0, Als0, Bls0, vA0, vB0, vAl0, vBl0);
      __syncthreads();
    }
  }
#undef LOAD_SET
#undef WRITE_SET
#undef COMPUTE_SET

#pragma unroll
  for (int m = 0; m < 4; ++m) {
    int row = m0 + wr * 64 + m * 16 + l4 * 4;
#pragma unroll
    for (int n = 0; n < 4; ++n) {
      int col = n0 + wc * 64 + n * 16 + l15;
#pragma unroll
      for (int q = 0; q < 4; ++q)
        part[((size_t)kz * partM + row + q) * N + col] = acc[m][n][q];
    }
  }
}

// split-K reduce: out[row][c] = sum_z part[z][row][c] + bias (+res). fp32 out.
__global__ __launch_bounds__(256) void reduce_splitk_kernel(
    const float* __restrict__ part, int partM, int nz,
    const float* __restrict__ bias, const int* __restrict__ tile_e,
    const float* __restrict__ res, float* __restrict__ outp, int N,
    const int* __restrict__ total_rows) {
  int row = blockIdx.x;
  if (total_rows && row >= *total_rows) return;
  const float* bb = bias;
  if (tile_e) bb = bias + (size_t)tile_e[row >> 7] * N;
  for (int c = threadIdx.x * 4; c < N; c += 1024) {
    float4 s = *(const float4*)(part + (size_t)row * N + c);
    for (int z = 1; z < nz; ++z) {
      float4 p = *(const float4*)(part + ((size_t)z * partM + row) * N + c);
      s.x += p.x; s.y += p.y; s.z += p.z; s.w += p.w;
    }
    s.x += bb[c]; s.y += bb[c + 1]; s.z += bb[c + 2]; s.w += bb[c + 3];
    if (res) {
      float4 r = *(const float4*)(res + (size_t)row * N + c);
      s.x += r.x; s.y += r.y; s.z += r.z; s.w += r.w;
    }
    *(float4*)(outp + (size_t)row * N + c) = s;
  }
}

// ---------------------------------------------------------------------------
// Fused attention: per block = 32 q-rows x one (b,h). Scores (fp32 VALU) into
// LDS, causal softmax in LDS, PV (fp32 VALU) from LDS. No scores HBM traffic.
// All LDS arrays col-XOR'd by (row&28): float4-aligned, <=2-way bank aliasing.
// Numerics match the previous 3-kernel fp32 path (router-decision safe).
__global__ __launch_bounds__(256) void fused_attn_kernel(
    const float* __restrict__ qkv, short* __restrict__ ctxh,
    short* __restrict__ ctxl) {
  __shared__ float Ss[32][512];  // scores/P, col ^ (row&28)
  __shared__ float Qs[32][64];   // Q tile,   col ^ (row&28)
  __shared__ float Ks[64][64];   // K then V, col ^ (row&28)
  int qt2 = blockIdx.x, bh = blockIdx.y;
  int b = bh / CH, h = bh % CH;
  int qrow0 = qt2 * 32;
  int ktmax = (qrow0 + 31) >> 6;
  int tid = threadIdx.x;
  int tx = tid & 15, ty = tid >> 4;
  int ry0 = ty * 2;

  // stage Q [32][64]
#pragma unroll
  for (int i = 0; i < 2; ++i) {
    int idx = i * 256 + tid;
    int r = idx >> 4, c4 = (idx & 15) * 4;
    float4 v = *(const float4*)(qkv + (size_t)(b * CS + qrow0 + r) * QKVP +
                                h * CHD + c4);
    *(float4*)&Qs[r][c4 ^ (r & 28)] = v;
  }
  __syncthreads();

  // phase 1: scores into Ss
  for (int kt = 0; kt <= ktmax; ++kt) {
    __syncthreads();
#pragma unroll
    for (int i = 0; i < 4; ++i) {
      int idx = i * 256 + tid;
      int r = idx >> 4, c4 = (idx & 15) * 4;
      float4 v = *(const float4*)(qkv + (size_t)(b * CS + kt * 64 + r) * QKVP +
                                  1024 + h * CHD + c4);
      *(float4*)&Ks[r][c4 ^ (r & 28)] = v;
    }
    __syncthreads();
    float acc[2][4] = {};
#pragma unroll 16
    for (int d = 0; d < 64; ++d) {
      float ra[2], rb[4];
#pragma unroll
      for (int i = 0; i < 2; ++i) ra[i] = Qs[ry0 + i][d ^ ((ry0 + i) & 28)];
#pragma unroll
      for (int j = 0; j < 4; ++j) {
        int c = tx * 4 + j;
        rb[j] = Ks[c][d ^ (c & 28)];
      }
#pragma unroll
      for (int i = 0; i < 2; ++i)
#pragma unroll
        for (int j = 0; j < 4; ++j) acc[i][j] += ra[i] * rb[j];
    }
#pragma unroll
    for (int i = 0; i < 2; ++i) {
      int r = ry0 + i;
      int gr = qrow0 + r;
#pragma unroll
      for (int j = 0; j < 4; ++j) {
        int gc = kt * 64 + tx * 4 + j;
        float s = (gc > gr) ? -1e30f : acc[i][j] * 0.125f;
        Ss[r][(kt * 64 + tx * 4 + j) ^ (r & 28)] = s;
      }
    }
  }
  __syncthreads();

  // phase 2: causal softmax per row (4 waves x 8 rows)
  int lane = tid & 63, wv = tid >> 6;
  int nc = (ktmax + 1) * 64;
  for (int rr = 0; rr < 8; ++rr) {
    int r = wv * 8 + rr;
    int xr = r & 28;
    int n = qrow0 + r + 1;  // valid cols
    float m = -1e30f;
    for (int c = lane; c < n; c += 64) m = fmaxf(m, Ss[r][c ^ xr]);
    for (int off = 32; off > 0; off >>= 1) m = fmaxf(m, __shfl_xor(m, off));
    float s = 0.f;
    for (int c = lane; c < n; c += 64) {
      float e = __expf(Ss[r][c ^ xr] - m);
      Ss[r][c ^ xr] = e;
      s += e;
    }
    for (int off = 32; off > 0; off >>= 1) s += __shfl_xor(s, off);
    float inv = 1.0f / s;
    for (int c = lane; c < nc; c += 64)
      Ss[r][c ^ xr] = (c < n) ? Ss[r][c ^ xr] * inv : 0.f;
  }
  __syncthreads();

  // phase 3: PV from LDS
  float acc2[2][4] = {};
  for (int kt = 0; kt <= ktmax; ++kt) {
#pragma unroll
    for (int i = 0; i < 4; ++i) {
      int idx = i * 256 + tid;
      int r = idx >> 4, c4 = (idx & 15) * 4;
      float4 v = *(const float4*)(qkv + (size_t)(b * CS + kt * 64 + r) * QKVP +
                                  2048 + h * CHD + c4);
      *(float4*)&Ks[r][c4 ^ (r & 28)] = v;
    }
    __syncthreads();
#pragma unroll 16
    for (int kk = 0; kk < 64; ++kk) {
      float ra[2];
#pragma unroll
      for (int i = 0; i < 2; ++i)
        ra[i] = Ss[ry0 + i][(kt * 64 + kk) ^ ((ry0 + i) & 28)];
      float4 rb4 = *(const float4*)&Ks[kk][(tx * 4) ^ (kk & 28)];
      float rb[4] = {rb4.x, rb4.y, rb4.z, rb4.w};
#pragma unroll
      for (int i = 0; i < 2; ++i)
#pragma unroll
        for (int j = 0; j < 4; ++j) acc2[i][j] += ra[i] * rb[j];
    }
    __syncthreads();
  }

#pragma unroll
  for (int i = 0; i < 2; ++i)
#pragma unroll
    for (int j = 0; j < 4; ++j) {
      size_t oi =
          (size_t)(b * CS + qrow0 + ry0 + i) * CD + h * CHD + tx * 4 + j;
      float v = acc2[i][j];
      short hi = f2bf(v);
      ctxh[oi] = hi;
      ctxl[oi] = f2bf(v - bf2f(hi));
    }
}

// ---------------------------------------------------------------------------
__global__ void zero_kernel(int* cursor) {
  int i = threadIdx.x;
  if (i < CE) cursor[i] = 0;
}

// Router: one WAVE per token (no atomics; stats in finalize).
__global__ __launch_bounds__(64) void router_kernel(
    const float* __restrict__ h2, const float* __restrict__ wr,
    const float* __restrict__ br, int* __restrict__ top_i,
    float* __restrict__ top_p, float* __restrict__ probs_out) {
  int t = blockIdx.x;
  int lane = threadIdx.x;
  float a[CE] = {};
  const float4* hv4 = (const float4*)(h2 + (size_t)t * CD);
#pragma unroll
  for (int i = 0; i < 4; ++i) {
    float4 hv = hv4[lane * 4 + i];
    const float* wrow = wr + (size_t)(lane * 16 + i * 4) * CE;
    float hh[4] = {hv.x, hv.y, hv.z, hv.w};
#pragma unroll
    for (int j = 0; j < 4; ++j)
#pragma unroll
      for (int e = 0; e < CE; ++e) a[e] += hh[j] * wrow[j * CE + e];
  }
#pragma unroll
  for (int e = 0; e < CE; ++e)
    for (int off = 32; off > 0; off >>= 1) a[e] += __shfl_down(a[e], off);
  if (lane == 0) {
    float probs[CE];
    float mx = -1e30f;
#pragma unroll
    for (int e = 0; e < CE; ++e) {
      a[e] += br[e];
      mx = fmaxf(mx, a[e]);
    }
    float sum = 0.f;
#pragma unroll
    for (int e = 0; e < CE; ++e) { probs[e] = __expf(a[e] - mx); sum += probs[e]; }
    float inv = 1.0f / sum;
#pragma unroll
    for (int e = 0; e < CE; ++e) {
      probs[e] *= inv;
      probs_out[t * CE + e] = probs[e];
    }
    int i1 = 0;
#pragma unroll
    for (int e = 1; e < CE; ++e) if (probs[e] > probs[i1]) i1 = e;
    int i2 = (i1 == 0) ? 1 : 0;
#pragma unroll
    for (int e = 0; e < CE; ++e)
      if (e != i1 && probs[e] > probs[i2]) i2 = e;
    float p1 = probs[i1], p2 = probs[i2];
    float s12 = p1 + p2;
    top_i[t * 2 + 0] = i1;
    top_i[t * 2 + 1] = i2;
    top_p[t * 2 + 0] = p1 / s12;
    top_p[t * 2 + 1] = p2 / s12;
  }
}

// Finalize (1 block): deterministic counts/psum, offsets, tile map, aux loss.
__global__ __launch_bounds__(256) void finalize_kernel(
    const int* __restrict__ top_i, const float* __restrict__ probs,
    int* __restrict__ offs, int* __restrict__ tile_e,
    int* __restrict__ total_padded, int* __restrict__ row_map,
    float* __restrict__ aux_out) {
  int tid = threadIdx.x;
  __shared__ float redp[256][CE];
  __shared__ int redc[256][CE];
  float lp[CE] = {};
  int lc[CE] = {};
  for (int t = tid; t < CT; t += 256) {
    lc[top_i[t * 2 + 0]]++;
    lc[top_i[t * 2 + 1]]++;
#pragma unroll
    for (int e = 0; e < CE; ++e) lp[e] += probs[t * CE + e];
  }
#pragma unroll
  for (int e = 0; e < CE; ++e) { redp[tid][e] = lp[e]; redc[tid][e] = lc[e]; }
  __syncthreads();
  for (int s = 128; s > 0; s >>= 1) {
    if (tid < s) {
#pragma unroll
      for (int e = 0; e < CE; ++e) {
        redp[tid][e] += redp[tid + s][e];
        redc[tid][e] += redc[tid + s][e];
      }
    }
    __syncthreads();
  }
  __shared__ int s_off[CE + 1];
  if (tid == 0) {
    int o = 0;
    for (int e = 0; e < CE; ++e) {
      s_off[e] = o;
      offs[e] = o;
      o += ((redc[0][e] + 127) >> 7) << 7;
    }
    s_off[CE] = o;
    offs[CE] = o;
    *total_padded = o;
    int nt = o >> 7;
    for (int i = 0; i < nt; ++i) {
      int e = 0;
      while (e < CE - 1 && i * 128 >= s_off[e + 1]) e++;
      tile_e[i] = e;
    }
    float aux = 0.f;
    for (int e = 0; e < CE; ++e)
      aux += ((float)redc[0][e] / (float)(CT * CK)) * (redp[0][e] / (float)CT);
    aux_out[0] = aux * (float)CE;
  }
  __syncthreads();
  for (int i = tid; i < MAXROWS; i += blockDim.x) row_map[i] = -1;
}

__global__ void gather_kernel(const int* __restrict__ top_i,
                              const int* __restrict__ offs,
                              int* __restrict__ cursor, int* __restrict__ row_map,
                              int* __restrict__ row_of) {
  int idx = blockIdx.x * blockDim.x + threadIdx.x;
  if (idx >= CT * CK) return;
  int e = top_i[idx];
  int pos = offs[e] + atomicAdd(&cursor[e], 1);
  row_map[pos] = idx >> 1;
  row_of[idx] = pos;
}

// Xg[row] = bf16(h2[row_map[row]]) or zeros for pad rows.
__global__ __launch_bounds__(256) void gatherx_kernel(
    const float* __restrict__ h2, const int* __restrict__ row_map,
    short* __restrict__ Xg) {
  int row = blockIdx.x;
  int tid = threadIdx.x;
  int tok = row_map[row];
  short4 o;
  if (tok < 0) {
    o = make_short4(0, 0, 0, 0);
  } else {
    float4 v = ((const float4*)(h2 + (size_t)tok * CD))[tid];
    o = make_short4(f2bf(v.x), f2bf(v.y), f2bf(v.z), f2bf(v.w));
  }
  ((short4*)(Xg + (size_t)row * CD))[tid] = o;
}

// out[t] = x1[t] + sum_k top_p[t,k] * ff_rows[row_of[t,k]]
__global__ __launch_bounds__(256) void combine_kernel(
    const float* __restrict__ x1, const float* __restrict__ ff_rows,
    const int* __restrict__ row_of, const float* __restrict__ top_p,
    float* __restrict__ out) {
  int t = blockIdx.x;
  int tid = threadIdx.x;
  float4 r = ((const float4*)(x1 + (size_t)t * CD))[tid];
#pragma unroll
  for (int s = 0; s < CK; ++s) {
    float w = top_p[t * 2 + s];
    int row = row_of[t * 2 + s];
    float4 f = ((const float4*)(ff_rows + (size_t)row * CD))[tid];
    r.x += w * f.x; r.y += w * f.y; r.z += w * f.z; r.w += w * f.w;
  }
  ((float4*)(out + (size_t)t * CD))[tid] = r;
}

// ---------------------------------------------------------------------------
extern "C" void kernel_launch(void* const* d_in, const int* in_sizes, int n_in,
                              void* d_out, int out_size, void* d_ws,
                              size_t ws_size, hipStream_t stream) {
  const float* x   = (const float*)d_in[0];
  const float* n1w = (const float*)d_in[1];
  const float* n2w = (const float*)d_in[2];
  const float* wq  = (const float*)d_in[3];
  const float* bq  = (const float*)d_in[4];
  const float* wk  = (const float*)d_in[5];
  const float* bk  = (const float*)d_in[6];
  const float* wv  = (const float*)d_in[7];
  const float* bv  = (const float*)d_in[8];
  const float* wo  = (const float*)d_in[9];
  const float* bo  = (const float*)d_in[10];
  const float* wr  = (const float*)d_in[11];
  const float* br  = (const float*)d_in[12];
  const float* w1  = (const float*)d_in[13];
  const float* b1  = (const float*)d_in[14];
  const float* w2  = (const float*)d_in[15];
  const float* b2  = (const float*)d_in[16];
  float* out = (float*)d_out;

  char* base = (char*)d_ws;
  size_t off = 0;
  auto alloc = [&](size_t bytes) -> void* {
    void* p = base + off;
    off += (bytes + 255) & ~(size_t)255;
    return p;
  };
  float* f_x1   = (float*)alloc((size_t)CT * CD * 4);
  float* f_h2   = (float*)alloc((size_t)CT * CD * 4);
  short* f_xg   = (short*)alloc((size_t)MAXROWS * CD * 2);
  short* f_hid  = (short*)alloc((size_t)MAXROWS * CF * 2);
  float* f_ff   = (float*)alloc((size_t)MAXROWS * CD * 4);
  short* f_hh   = (short*)alloc((size_t)CT * CD * 2);
  short* f_hl   = (short*)alloc((size_t)CT * CD * 2);
  short* f_wqkvh = (short*)alloc((size_t)QKVP * CD * 2);
  short* f_wqkvl = (short*)alloc((size_t)QKVP * CD * 2);
  float* f_qkv  = (float*)alloc((size_t)CT * QKVP * 4);
  short* f_ctxh = (short*)alloc((size_t)CT * CD * 2);
  short* f_ctxl = (short*)alloc((size_t)CT * CD * 2);
  short* f_woth = (short*)alloc((size_t)CD * CD * 2);
  short* f_wotl = (short*)alloc((size_t)CD * CD * 2);
  float* f_bqkv = (float*)alloc(QKVP * 4);
  float* f_topp = (float*)alloc(CT * CK * 4);
  float* f_probs = (float*)alloc(CT * CE * 4);
  int* i_topi   = (int*)alloc(CT * CK * 4);
  int* i_rowof  = (int*)alloc(CT * CK * 4);
  int* i_rowmap = (int*)alloc(MAXROWS * 4);
  int* i_cursor = (int*)alloc(CE * 4);
  int* i_offs   = (int*)alloc((CE + 1) * 4);
  int* i_tile   = (int*)alloc(MAXTILES * 4);
  int* i_total  = (int*)alloc(4);
  // G (64MB): w1t -> w2t (sequential reuse)
  short* f_wG = (short*)alloc((size_t)CE * CD * CF * 2);
  short* f_w1t = f_wG;
  short* f_w2t = f_wG;
  // Rs (48MB): QKV partials -> WO partials -> GEMM2 partials (disjoint)
  void* Rs = alloc((size_t)4 * MAXROWS * CD * 4);
  float* f_partqkv = (float*)Rs;
  float* f_partwo = (float*)Rs;
  float* f_partg2 = (float*)Rs;

  dim3 b256(256);

  zero_kernel<<<1, 64, 0, stream>>>(i_cursor);
  pack_bias_kernel<<<QKVP / 256, b256, 0, stream>>>(bq, bk, bv, f_bqkv);
  // weight preprocessing (hi/lo for attention, hi-only for experts)
  transpose_convert_kernel<<<dim3(16, 16, 1), b256, 0, stream>>>(
      wq, f_wqkvh + 0 * (size_t)CD * CD, f_wqkvl + 0 * (size_t)CD * CD, CD, CD);
  transpose_convert_kernel<<<dim3(16, 16, 1), b256, 0, stream>>>(
      wk, f_wqkvh + 1 * (size_t)CD * CD, f_wqkvl + 1 * (size_t)CD * CD, CD, CD);
  transpose_convert_kernel<<<dim3(16, 16, 1), b256, 0, stream>>>(
      wv, f_wqkvh + 2 * (size_t)CD * CD, f_wqkvl + 2 * (size_t)CD * CD, CD, CD);
  transpose_convert_kernel<<<dim3(16, 16, 1), b256, 0, stream>>>(
      wo, f_woth, f_wotl, CD, CD);
  transpose_convert_kernel<<<dim3(CF / 64, CD / 64, CE), b256, 0, stream>>>(
      w1, f_w1t, nullptr, CD, CF);

  // ---- attention ----
  rmsnorm_kernel<2><<<CT, b256, 0, stream>>>(x, n1w, f_hh, f_hl);
  mfma_gemm_kernel<1><<<dim3(QKVP / 128, CT / 128, 2), b256, 0, stream>>>(
      f_hh, f_hl, f_wqkvh, f_wqkvl, f_partqkv, CT, QKVP, CD);
  reduce_splitk_kernel<<<CT, b256, 0, stream>>>(f_partqkv, CT, 2, f_bqkv,
                                                nullptr, nullptr, f_qkv, QKVP,
                                                nullptr);
  fused_attn_kernel<<<dim3(CS / 32, CBH), b256, 0, stream>>>(f_qkv, f_ctxh,
                                                             f_ctxl);
  mfma_gemm_kernel<1><<<dim3(CD / 128, CT / 128, 4), b256, 0, stream>>>(
      f_ctxh, f_ctxl, f_woth, f_wotl, f_partwo, CT, CD, CD);
  reduce_splitk_kernel<<<CT, b256, 0, stream>>>(f_partwo, CT, 4, bo, nullptr, x,
                                                f_x1, CD, nullptr);

  // ---- MoE ----
  rmsnorm_kernel<0><<<CT, b256, 0, stream>>>(f_x1, n2w, f_h2, nullptr);
  router_kernel<<<CT, dim3(64), 0, stream>>>(f_h2, wr, br, i_topi, f_topp,
                                             f_probs);
  finalize_kernel<<<1, 256, 0, stream>>>(i_topi, f_probs, i_offs, i_tile,
                                         i_total, i_rowmap,
                                         out + (size_t)CT * CD);
  gather_kernel<<<(CT * CK + 255) / 256, b256, 0, stream>>>(i_topi, i_offs,
                                                            i_cursor, i_rowmap,
                                                            i_rowof);
  gatherx_kernel<<<MAXROWS, b256, 0, stream>>>(f_h2, i_rowmap, f_xg);

  moe_gemm_kernel<1, 1><<<dim3(CF / 256, MAXTILES, 1), dim3(512), 0, stream>>>(
      f_xg, f_w1t, b1, f_hid, nullptr, 0, CF, CD, i_tile, i_total);
  transpose_convert_kernel<<<dim3(CD / 64, CF / 64, CE), b256, 0, stream>>>(
      w2, f_w2t, nullptr, CF, CD);
  moe_gemm_kernel<0, 0><<<dim3(CD / 256, MAXTILES, 4), dim3(512), 0, stream>>>(
      f_hid, f_w2t, nullptr, nullptr, f_partg2, MAXROWS, CD, CF, i_tile,
      i_total);
  reduce_splitk_kernel<<<MAXROWS, b256, 0, stream>>>(f_partg2, MAXROWS, 4, b2,
                                                     i_tile, nullptr, f_ff, CD,
                                                     i_total);

  combine_kernel<<<CT, b256, 0, stream>>>(f_x1, f_ff, i_rowof, f_topp, out);
}

// Round 10
// 403.011 us; speedup vs baseline: 1.1650x; 1.1650x over previous
//
#include <hip/hip_runtime.h>
#include <math.h>

// Problem constants
#define CB 2
#define CS 512
#define CD 1024
#define CH 16
#define CHD 64
#define CF 4096
#define CE 8
#define CK 2
#define CT (CB*CS)      // 1024 tokens
#define CBH (CB*CH)     // 32 (batch*heads)
#define CEPS 1e-6f
#define QKVP 3072       // packed q|k|v row pitch
#define MAXROWS 3072    // 2048 + 8*127 padded to 128
#define MAXTILES (MAXROWS/128)

typedef __attribute__((ext_vector_type(8))) short bf16x8;
typedef __attribute__((ext_vector_type(4))) float f32x4;

__device__ __forceinline__ short f2bf(float f) {
  unsigned u = __float_as_uint(f);
  unsigned r = (u + 0x7FFF + ((u >> 16) & 1)) >> 16;
  return (short)r;
}
__device__ __forceinline__ float bf2f(short h) {
  return __uint_as_float(((unsigned)(unsigned short)h) << 16);
}

__device__ __forceinline__ void gload_lds16(const void* g, void* l) {
  __builtin_amdgcn_global_load_lds(
      (const __attribute__((address_space(1))) unsigned int*)g,
      (__attribute__((address_space(3))) unsigned int*)l, 16, 0, 0);
}

// ---------------------------------------------------------------------------
// RMSNorm. MODE 0: fp32 out (outA). MODE 2: hi/lo bf16 planes (outA=hi, outB=lo)
template <int MODE>
__global__ __launch_bounds__(256) void rmsnorm_kernel(
    const float* __restrict__ x, const float* __restrict__ w,
    void* __restrict__ outA, void* __restrict__ outB) {
  int t = blockIdx.x;
  int tid = threadIdx.x;
  float4 xv = ((const float4*)(x + (size_t)t * CD))[tid];
  float ss = xv.x*xv.x + xv.y*xv.y + xv.z*xv.z + xv.w*xv.w;
  for (int off = 32; off > 0; off >>= 1) ss += __shfl_down(ss, off);
  __shared__ float red[4];
  __shared__ float s_scale;
  int lane = tid & 63, wid = tid >> 6;
  if (lane == 0) red[wid] = ss;
  __syncthreads();
  if (tid == 0) {
    float tot = red[0] + red[1] + red[2] + red[3];
    s_scale = rsqrtf(tot / (float)CD + CEPS);
  }
  __syncthreads();
  float sc = s_scale;
  float4 wv = ((const float4*)w)[tid];
  float o[4] = {xv.x * sc * wv.x, xv.y * sc * wv.y,
                xv.z * sc * wv.z, xv.w * sc * wv.w};
  if (MODE == 0) {
    ((float4*)((float*)outA + (size_t)t * CD))[tid] =
        make_float4(o[0], o[1], o[2], o[3]);
  } else {
    short4 hi, lo;
    short* hp = (short*)&hi; short* lp = (short*)&lo;
#pragma unroll
    for (int i = 0; i < 4; ++i) {
      short h = f2bf(o[i]);
      hp[i] = h;
      lp[i] = f2bf(o[i] - bf2f(h));
    }
    ((short4*)((short*)outA + (size_t)t * CD))[tid] = hi;
    ((short4*)((short*)outB + (size_t)t * CD))[tid] = lo;
  }
}

// ---------------------------------------------------------------------------
// Tiled transpose+convert, 64x64 tile, 16B short8 stores:
// W[e][Kd][Nd] f32 -> Wth[e][Nd][Kd] bf16 (+ optional lo plane).
__global__ __launch_bounds__(256) void transpose_convert_kernel(
    const float* __restrict__ W, short* __restrict__ Wth,
    short* __restrict__ Wtl, int Kd, int Nd) {
  int e = blockIdx.z;
  const float* Wb = W + (size_t)e * Kd * Nd;
  size_t obase = (size_t)e * Kd * Nd;
  int n0 = blockIdx.x * 64, k0 = blockIdx.y * 64;
  __shared__ float t[64][65];
  int tid = threadIdx.x;
#pragma unroll
  for (int i = 0; i < 4; ++i) {
    int idx = i * 256 + tid;
    int r = idx >> 4, c4 = (idx & 15) * 4;
    float4 v = *(const float4*)(Wb + (size_t)(k0 + r) * Nd + n0 + c4);
    t[r][c4] = v.x; t[r][c4 + 1] = v.y; t[r][c4 + 2] = v.z; t[r][c4 + 3] = v.w;
  }
  __syncthreads();
  int n = tid >> 2, k16 = (tid & 3) * 16;
  short th[16], tl[16];
#pragma unroll
  for (int j = 0; j < 16; ++j) {
    float v = t[k16 + j][n];
    short hi = f2bf(v);
    th[j] = hi;
    tl[j] = f2bf(v - bf2f(hi));
  }
  size_t oo = obase + (size_t)(n0 + n) * Kd + k0 + k16;
  ((int4*)(Wth + oo))[0] = ((int4*)th)[0];
  ((int4*)(Wth + oo + 8))[0] = ((int4*)th)[1];
  if (Wtl) {
    ((int4*)(Wtl + oo))[0] = ((int4*)tl)[0];
    ((int4*)(Wtl + oo + 8))[0] = ((int4*)tl)[1];
  }
}

__global__ void pack_bias_kernel(const float* __restrict__ bq,
                                 const float* __restrict__ bk,
                                 const float* __restrict__ bv,
                                 float* __restrict__ out) {
  int i = blockIdx.x * 256 + threadIdx.x;
  if (i < QKVP)
    out[i] = (i < 1024) ? bq[i] : (i < 2048 ? bk[i - 1024] : bv[i - 2048]);
}

// ---------------------------------------------------------------------------
// MoE grouped GEMM: BM=128, BN=256, BK=64, 8 waves.
template <int SILU, int OUTBF>
__global__ __launch_bounds__(512) void moe_gemm_kernel(
    const short* __restrict__ A, const short* __restrict__ Bt,
    const float* __restrict__ bias, void* __restrict__ Cout,
    float* __restrict__ part, int partM, int N, int K,
    const int* __restrict__ tile_e, const int* __restrict__ total_rows) {
  __shared__ __align__(16) short A0[128 * 64], A1[128 * 64];
  __shared__ __align__(16) short B0[256 * 64], B1[256 * 64];
  int tid = threadIdx.x;
  int m0 = blockIdx.y * 128, n0 = blockIdx.x * 256;
  if (m0 >= *total_rows) return;
  int e = tile_e[blockIdx.y];
  const short* Bb = Bt + (size_t)e * N * K;
  const float* biasb = bias ? bias + (size_t)e * N : nullptr;
  int kz = blockIdx.z;
  int kchunk = K / gridDim.z;
  int kbeg = kz * kchunk;
  int nsteps = kchunk >> 6;
  int lane = tid & 63, w = tid >> 6;
  int wr = w >> 2, wc = w & 3;
  int l15 = lane & 15, l4 = lane >> 4;
  f32x4 acc[4][4] = {};

#define STAGE(AS_, BS_, KK)                                                   \
  {                                                                           \
    _Pragma("unroll") for (int i = 0; i < 2; ++i) {                           \
      int c = i * 512 + tid;                                                  \
      int r = c >> 3, gs = c & 7;                                             \
      int g = gs ^ (r & 7);                                                   \
      gload_lds16(A + (size_t)(m0 + r) * K + (KK) + g * 8, &AS_[c * 8]);      \
    }                                                                         \
    _Pragma("unroll") for (int i = 0; i < 4; ++i) {                           \
      int c = i * 512 + tid;                                                  \
      int r = c >> 3, gs = c & 7;                                             \
      int g = gs ^ (r & 7);                                                   \
      gload_lds16(Bb + (size_t)(n0 + r) * K + (KK) + g * 8, &BS_[c * 8]);     \
    }                                                                         \
  }

#define COMPUTE(AS_, BS_)                                                     \
  {                                                                           \
    _Pragma("unroll") for (int ks = 0; ks < 2; ++ks) {                        \
      bf16x8 a[4], b[4];                                                      \
      _Pragma("unroll") for (int m = 0; m < 4; ++m) {                         \
        int row = wr * 64 + m * 16 + l15;                                     \
        int slot = (ks * 4 + l4) ^ (row & 7);                                 \
        a[m] = *(const bf16x8*)&AS_[(row * 8 + slot) * 8];                    \
      }                                                                       \
      _Pragma("unroll") for (int n = 0; n < 4; ++n) {                         \
        int row = wc * 64 + n * 16 + l15;                                     \
        int slot = (ks * 4 + l4) ^ (row & 7);                                 \
        b[n] = *(const bf16x8*)&BS_[(row * 8 + slot) * 8];                    \
      }                                                                       \
      _Pragma("unroll") for (int m = 0; m < 4; ++m)                           \
      _Pragma("unroll") for (int n = 0; n < 4; ++n)                           \
        acc[m][n] = __builtin_amdgcn_mfma_f32_16x16x32_bf16(a[m], b[n],       \
                                                            acc[m][n], 0, 0, 0); \
    }                                                                         \
  }

  STAGE(A0, B0, kbeg);
  __syncthreads();
  for (int s = 0; s < nsteps; s += 2) {
    int k0 = kbeg + (s << 6);
    bool has1 = (s + 1 < nsteps), has2 = (s + 2 < nsteps);
    if (has1) STAGE(A1, B1, k0 + 64);
    COMPUTE(A0, B0);
    __syncthreads();
    if (has1) {
      if (has2) STAGE(A0, B0, k0 + 128);
      COMPUTE(A1, B1);
      __syncthreads();
    }
  }
#undef STAGE
#undef COMPUTE

  if (gridDim.z > 1) {
#pragma unroll
    for (int m = 0; m < 4; ++m) {
      int row = m0 + wr * 64 + m * 16 + l4 * 4;
#pragma unroll
      for (int n = 0; n < 4; ++n) {
        int col = n0 + wc * 64 + n * 16 + l15;
#pragma unroll
        for (int q = 0; q < 4; ++q)
          part[((size_t)kz * partM + row + q) * N + col] = acc[m][n][q];
      }
    }
    return;
  }
  float* outf = (float*)Cout;
  short* outb = (short*)Cout;
#pragma unroll
  for (int m = 0; m < 4; ++m) {
    int row = m0 + wr * 64 + m * 16 + l4 * 4;
#pragma unroll
    for (int n = 0; n < 4; ++n) {
      int col = n0 + wc * 64 + n * 16 + l15;
      float bv = biasb[col];
#pragma unroll
      for (int q = 0; q < 4; ++q) {
        float v = acc[m][n][q] + bv;
        if (SILU) v = v / (1.f + __expf(-v));
        if (OUTBF) outb[(size_t)(row + q) * N + col] = f2bf(v);
        else outf[(size_t)(row + q) * N + col] = v;
      }
    }
  }
}

// ---------------------------------------------------------------------------
// Attention MFMA GEMM: 128x128, BK=32, 4 waves, hi/lo reg-staged, split-K.
template <int LO>
__global__ __launch_bounds__(256) void mfma_gemm_kernel(
    const short* __restrict__ Ah, const short* __restrict__ Al,
    const short* __restrict__ Bh, const short* __restrict__ Bl,
    float* __restrict__ part, int partM, int N, int K) {
  __shared__ short As0[4096], Bs0[4096], As1[4096], Bs1[4096];
  __shared__ short Als0[LO ? 4096 : 64], Bls0[LO ? 4096 : 64];
  __shared__ short Als1[LO ? 4096 : 64], Bls1[LO ? 4096 : 64];
  int tid = threadIdx.x;
  int m0 = blockIdx.y * 128, n0 = blockIdx.x * 128;
  int kz = blockIdx.z;
  int kchunk = K / gridDim.z;
  int kbeg = kz * kchunk;
  int nsteps = kchunk >> 5;
  int lane = tid & 63, w = tid >> 6;
  int wr = w >> 1, wc = w & 1;
  int l15 = lane & 15, l4 = lane >> 4;
  int xorl = (l15 & 3) ^ ((l15 >> 2) & 3);
  f32x4 acc[4][4] = {};
  bf16x8 vA0[2], vB0[2], vAl0[2], vBl0[2];
  bf16x8 vA1[2], vB1[2], vAl1[2], vBl1[2];

#define LOAD_SET(VA, VB, VAL, VBL, KK)                                        \
  {                                                                           \
    _Pragma("unroll") for (int ic = 0; ic < 2; ++ic) {                        \
      int c = ic * 256 + tid;                                                 \
      int r = c >> 2, g = c & 3;                                              \
      size_t ao = (size_t)(m0 + r) * K + (KK) + g * 8;                        \
      size_t bo = (size_t)(n0 + r) * K + (KK) + g * 8;                        \
      VA[ic] = *(const bf16x8*)(Ah + ao);                                     \
      VB[ic] = *(const bf16x8*)(Bh + bo);                                     \
      if (LO) {                                                               \
        VAL[ic] = *(const bf16x8*)(Al + ao);                                  \
        VBL[ic] = *(const bf16x8*)(Bl + bo);                                  \
      }                                                                       \
    }                                                                         \
  }

#define WRITE_SET(AS_, BS_, ALS_, BLS_, VA, VB, VAL, VBL)                     \
  {                                                                           \
    _Pragma("unroll") for (int ic = 0; ic < 2; ++ic) {                        \
      int c = ic * 256 + tid;                                                 \
      int r = c >> 2, g = c & 3;                                              \
      int ch = (r * 4 + (g ^ (r & 3) ^ ((r >> 2) & 3))) * 8;                  \
      *(bf16x8*)&AS_[ch] = VA[ic];                                            \
      *(bf16x8*)&BS_[ch] = VB[ic];                                            \
      if (LO) {                                                               \
        *(bf16x8*)&ALS_[ch] = VAL[ic];                                        \
        *(bf16x8*)&BLS_[ch] = VBL[ic];                                        \
      }                                                                       \
    }                                                                         \
  }

#define COMPUTE_SET(AS_, BS_, ALS_, BLS_)                                     \
  {                                                                           \
    bf16x8 ah[4], al[4];                                                      \
    _Pragma("unroll") for (int m = 0; m < 4; ++m) {                           \
      int row = wr * 64 + m * 16 + l15;                                       \
      int idx = (row * 4 + (l4 ^ xorl)) * 8;                                  \
      ah[m] = *(const bf16x8*)&AS_[idx];                                      \
      if (LO) al[m] = *(const bf16x8*)&ALS_[idx];                             \
    }                                                                         \
    _Pragma("unroll") for (int n = 0; n < 4; ++n) {                           \
      int row = wc * 64 + n * 16 + l15;                                       \
      int idx = (row * 4 + (l4 ^ xorl)) * 8;                                  \
      bf16x8 bhn = *(const bf16x8*)&BS_[idx];                                 \
      bf16x8 bln;                                                             \
      if (LO) bln = *(const bf16x8*)&BLS_[idx];                               \
      _Pragma("unroll") for (int m = 0; m < 4; ++m) {                         \
        acc[m][n] = __builtin_amdgcn_mfma_f32_16x16x32_bf16(ah[m], bhn,       \
                                                            acc[m][n], 0, 0, 0); \
        if (LO) {                                                             \
          acc[m][n] = __builtin_amdgcn_mfma_f32_16x16x32_bf16(al[m], bhn,     \
                                                              acc[m][n], 0, 0, 0); \
          acc[m][n] = __builtin_amdgcn_mfma_f32_16x16x32_bf16(ah[m], bln,     \
                                                              acc[m][n], 0, 0, 0); \
        }                                                                     \
      }                                                                       \
    }                                                                         \
  }

  LOAD_SET(vA0, vB0, vAl0, vBl0, kbeg);
  WRITE_SET(As0, Bs0, Als0, Bls0, vA0, vB0, vAl0, vBl0);
  __syncthreads();
  for (int s = 0; s < nsteps; s += 2) {
    int k0 = kbeg + (s << 5);
    bool has1 = (s + 1 < nsteps), has2 = (s + 2 < nsteps);
    if (has1) LOAD_SET(vA1, vB1, vAl1, vBl1, k0 + 32);
    COMPUTE_SET(As0, Bs0, Als0, Bls0);
    if (has1) WRITE_SET(As1, Bs1, Als1, Bls1, vA1, vB1, vAl1, vBl1);
    __syncthreads();
    if (has1) {
      if (has2) LOAD_SET(vA0, vB0, vAl0, vBl0, k0 + 64);
      COMPUTE_SET(As1, Bs1, Als1, Bls1);
      if (has2) WRITE_SET(As0, Bs0, Als0, Bls0, vA0, vB0, vAl0, vBl0);
      __syncthreads();
    }
  }
#undef LOAD_SET
#undef WRITE_SET
#undef COMPUTE_SET

#pragma unroll
  for (int m = 0; m < 4; ++m) {
    int row = m0 + wr * 64 + m * 16 + l4 * 4;
#pragma unroll
    for (int n = 0; n < 4; ++n) {
      int col = n0 + wc * 64 + n * 16 + l15;
#pragma unroll
      for (int q = 0; q < 4; ++q)
        part[((size_t)kz * partM + row + q) * N + col] = acc[m][n][q];
    }
  }
}

// split-K reduce: out[row][c] = sum_z part[z][row][c] + bias (+res). fp32 out.
__global__ __launch_bounds__(256) void reduce_splitk_kernel(
    const float* __restrict__ part, int partM, int nz,
    const float* __restrict__ bias, const int* __restrict__ tile_e,
    const float* __restrict__ res, float* __restrict__ outp, int N,
    const int* __restrict__ total_rows) {
  int row = blockIdx.x;
  if (total_rows && row >= *total_rows) return;
  const float* bb = bias;
  if (tile_e) bb = bias + (size_t)tile_e[row >> 7] * N;
  for (int c = threadIdx.x * 4; c < N; c += 1024) {
    float4 s = *(const float4*)(part + (size_t)row * N + c);
    for (int z = 1; z < nz; ++z) {
      float4 p = *(const float4*)(part + ((size_t)z * partM + row) * N + c);
      s.x += p.x; s.y += p.y; s.z += p.z; s.w += p.w;
    }
    s.x += bb[c]; s.y += bb[c + 1]; s.z += bb[c + 2]; s.w += bb[c + 3];
    if (res) {
      float4 r = *(const float4*)(res + (size_t)row * N + c);
      s.x += r.x; s.y += r.y; s.z += r.z; s.w += r.w;
    }
    *(float4*)(outp + (size_t)row * N + c) = s;
  }
}

// ---------------------------------------------------------------------------
// Fused attention v2: per block = 16 q-rows x one (b,h). 256 threads,
// thread (ty=row 0..15, tx=col-group 0..15). LDS ~55KB -> 2 blocks/CU.
// K staged TRANSPOSED Kt[d][c] (pad 68): inner-loop read is float4 at
// Kt[d][tx*4] = 16 stride-4 addrs + 4-way broadcast -> <=2-way (free).
// Ss row stride 520 (=8 mod 32): rows separate banks for softmax/PV reads.
// Numerics identical to the 3-kernel fp32 path (router-decision safe).
__global__ __launch_bounds__(256) void fused_attn_kernel(
    const float* __restrict__ qkv, short* __restrict__ ctxh,
    short* __restrict__ ctxl) {
  __shared__ float Ss[16][520];  // scores/P rows (<=512 cols)
  __shared__ float Qs[16][68];   // Q tile
  __shared__ float KVs[64][68];  // Kt[d][c] in phase 1; V[k][d] in phase 3
  int qt = blockIdx.x, bh = blockIdx.y;
  int b = bh / CH, h = bh % CH;
  int qrow0 = qt * 16;
  int ktmax = (qrow0 + 15) >> 6;
  int tid = threadIdx.x;
  int tx = tid & 15, ty = tid >> 4;  // ty = this thread's q-row

  // stage Q [16][64]: one float4 per thread
  {
    float4 v = *(const float4*)(qkv + (size_t)(b * CS + qrow0 + ty) * QKVP +
                                h * CHD + tx * 4);
    *(float4*)&Qs[ty][tx * 4] = v;
  }

  // phase 1: scores into Ss
  for (int kt = 0; kt <= ktmax; ++kt) {
    __syncthreads();
    // stage K transposed: Kt[d][c] = K[c][d]
#pragma unroll
    for (int i = 0; i < 4; ++i) {
      int idx = i * 256 + tid;
      int r = idx >> 4, c4 = (idx & 15) * 4;
      float4 v = *(const float4*)(qkv + (size_t)(b * CS + kt * 64 + r) * QKVP +
                                  1024 + h * CHD + c4);
      KVs[c4 + 0][r] = v.x;
      KVs[c4 + 1][r] = v.y;
      KVs[c4 + 2][r] = v.z;
      KVs[c4 + 3][r] = v.w;
    }
    __syncthreads();
    float acc[4] = {};
#pragma unroll 8
    for (int d = 0; d < 64; ++d) {
      float ra = Qs[ty][d];
      float4 rb = *(const float4*)&KVs[d][tx * 4];
      acc[0] += ra * rb.x;
      acc[1] += ra * rb.y;
      acc[2] += ra * rb.z;
      acc[3] += ra * rb.w;
    }
    int gr = qrow0 + ty;
#pragma unroll
    for (int j = 0; j < 4; ++j) {
      int gc = kt * 64 + tx * 4 + j;
      Ss[ty][gc] = (gc > gr) ? -1e30f : acc[j] * 0.125f;
    }
  }
  __syncthreads();

  // phase 2: causal softmax; wave wv handles rows 4wv..4wv+3
  int lane = tid & 63, wv = tid >> 6;
  int nc = (ktmax + 1) * 64;
  for (int rr = 0; rr < 4; ++rr) {
    int r = wv * 4 + rr;
    int n = qrow0 + r + 1;
    float m = -1e30f;
    for (int c = lane; c < n; c += 64) m = fmaxf(m, Ss[r][c]);
    for (int off = 32; off > 0; off >>= 1) m = fmaxf(m, __shfl_xor(m, off));
    float s = 0.f;
    for (int c = lane; c < n; c += 64) {
      float e = __expf(Ss[r][c] - m);
      Ss[r][c] = e;
      s += e;
    }
    for (int off = 32; off > 0; off >>= 1) s += __shfl_xor(s, off);
    float inv = 1.0f / s;
    for (int c = lane; c < nc; c += 64)
      Ss[r][c] = (c < n) ? Ss[r][c] * inv : 0.f;
  }

  // phase 3: PV from LDS (V row-major)
  float acc2[4] = {};
  for (int kt = 0; kt <= ktmax; ++kt) {
    __syncthreads();
#pragma unroll
    for (int i = 0; i < 4; ++i) {
      int idx = i * 256 + tid;
      int r = idx >> 4, c4 = (idx & 15) * 4;
      *(float4*)&KVs[r][c4] =
          *(const float4*)(qkv + (size_t)(b * CS + kt * 64 + r) * QKVP + 2048 +
                           h * CHD + c4);
    }
    __syncthreads();
#pragma unroll 8
    for (int kk = 0; kk < 64; ++kk) {
      float ra = Ss[ty][kt * 64 + kk];
      float4 rb = *(const float4*)&KVs[kk][tx * 4];
      acc2[0] += ra * rb.x;
      acc2[1] += ra * rb.y;
      acc2[2] += ra * rb.z;
      acc2[3] += ra * rb.w;
    }
  }

#pragma unroll
  for (int j = 0; j < 4; ++j) {
    size_t oi = (size_t)(b * CS + qrow0 + ty) * CD + h * CHD + tx * 4 + j;
    float v = acc2[j];
    short hi = f2bf(v);
    ctxh[oi] = hi;
    ctxl[oi] = f2bf(v - bf2f(hi));
  }
}

// ---------------------------------------------------------------------------
__global__ void zero_kernel(int* cursor) {
  int i = threadIdx.x;
  if (i < CE) cursor[i] = 0;
}

// Router: one WAVE per token (no atomics; stats in finalize).
__global__ __launch_bounds__(64) void router_kernel(
    const float* __restrict__ h2, const float* __restrict__ wr,
    const float* __restrict__ br, int* __restrict__ top_i,
    float* __restrict__ top_p, float* __restrict__ probs_out) {
  int t = blockIdx.x;
  int lane = threadIdx.x;
  float a[CE] = {};
  const float4* hv4 = (const float4*)(h2 + (size_t)t * CD);
#pragma unroll
  for (int i = 0; i < 4; ++i) {
    float4 hv = hv4[lane * 4 + i];
    const float* wrow = wr + (size_t)(lane * 16 + i * 4) * CE;
    float hh[4] = {hv.x, hv.y, hv.z, hv.w};
#pragma unroll
    for (int j = 0; j < 4; ++j)
#pragma unroll
      for (int e = 0; e < CE; ++e) a[e] += hh[j] * wrow[j * CE + e];
  }
#pragma unroll
  for (int e = 0; e < CE; ++e)
    for (int off = 32; off > 0; off >>= 1) a[e] += __shfl_down(a[e], off);
  if (lane == 0) {
    float probs[CE];
    float mx = -1e30f;
#pragma unroll
    for (int e = 0; e < CE; ++e) {
      a[e] += br[e];
      mx = fmaxf(mx, a[e]);
    }
    float sum = 0.f;
#pragma unroll
    for (int e = 0; e < CE; ++e) { probs[e] = __expf(a[e] - mx); sum += probs[e]; }
    float inv = 1.0f / sum;
#pragma unroll
    for (int e = 0; e < CE; ++e) {
      probs[e] *= inv;
      probs_out[t * CE + e] = probs[e];
    }
    int i1 = 0;
#pragma unroll
    for (int e = 1; e < CE; ++e) if (probs[e] > probs[i1]) i1 = e;
    int i2 = (i1 == 0) ? 1 : 0;
#pragma unroll
    for (int e = 0; e < CE; ++e)
      if (e != i1 && probs[e] > probs[i2]) i2 = e;
    float p1 = probs[i1], p2 = probs[i2];
    float s12 = p1 + p2;
    top_i[t * 2 + 0] = i1;
    top_i[t * 2 + 1] = i2;
    top_p[t * 2 + 0] = p1 / s12;
    top_p[t * 2 + 1] = p2 / s12;
  }
}

// Finalize (1 block): deterministic counts/psum, offsets, tile map, aux loss.
__global__ __launch_bounds__(256) void finalize_kernel(
    const int* __restrict__ top_i, const float* __restrict__ probs,
    int* __restrict__ offs, int* __restrict__ tile_e,
    int* __restrict__ total_padded, int* __restrict__ row_map,
    float* __restrict__ aux_out) {
  int tid = threadIdx.x;
  __shared__ float redp[256][CE];
  __shared__ int redc[256][CE];
  float lp[CE] = {};
  int lc[CE] = {};
  for (int t = tid; t < CT; t += 256) {
    lc[top_i[t * 2 + 0]]++;
    lc[top_i[t * 2 + 1]]++;
#pragma unroll
    for (int e = 0; e < CE; ++e) lp[e] += probs[t * CE + e];
  }
#pragma unroll
  for (int e = 0; e < CE; ++e) { redp[tid][e] = lp[e]; redc[tid][e] = lc[e]; }
  __syncthreads();
  for (int s = 128; s > 0; s >>= 1) {
    if (tid < s) {
#pragma unroll
      for (int e = 0; e < CE; ++e) {
        redp[tid][e] += redp[tid + s][e];
        redc[tid][e] += redc[tid + s][e];
      }
    }
    __syncthreads();
  }
  __shared__ int s_off[CE + 1];
  if (tid == 0) {
    int o = 0;
    for (int e = 0; e < CE; ++e) {
      s_off[e] = o;
      offs[e] = o;
      o += ((redc[0][e] + 127) >> 7) << 7;
    }
    s_off[CE] = o;
    offs[CE] = o;
    *total_padded = o;
    int nt = o >> 7;
    for (int i = 0; i < nt; ++i) {
      int e = 0;
      while (e < CE - 1 && i * 128 >= s_off[e + 1]) e++;
      tile_e[i] = e;
    }
    float aux = 0.f;
    for (int e = 0; e < CE; ++e)
      aux += ((float)redc[0][e] / (float)(CT * CK)) * (redp[0][e] / (float)CT);
    aux_out[0] = aux * (float)CE;
  }
  __syncthreads();
  for (int i = tid; i < MAXROWS; i += blockDim.x) row_map[i] = -1;
}

__global__ void gather_kernel(const int* __restrict__ top_i,
                              const int* __restrict__ offs,
                              int* __restrict__ cursor, int* __restrict__ row_map,
                              int* __restrict__ row_of) {
  int idx = blockIdx.x * blockDim.x + threadIdx.x;
  if (idx >= CT * CK) return;
  int e = top_i[idx];
  int pos = offs[e] + atomicAdd(&cursor[e], 1);
  row_map[pos] = idx >> 1;
  row_of[idx] = pos;
}

// Xg[row] = bf16(h2[row_map[row]]) or zeros for pad rows.
__global__ __launch_bounds__(256) void gatherx_kernel(
    const float* __restrict__ h2, const int* __restrict__ row_map,
    short* __restrict__ Xg) {
  int row = blockIdx.x;
  int tid = threadIdx.x;
  int tok = row_map[row];
  short4 o;
  if (tok < 0) {
    o = make_short4(0, 0, 0, 0);
  } else {
    float4 v = ((const float4*)(h2 + (size_t)tok * CD))[tid];
    o = make_short4(f2bf(v.x), f2bf(v.y), f2bf(v.z), f2bf(v.w));
  }
  ((short4*)(Xg + (size_t)row * CD))[tid] = o;
}

// out[t] = x1[t] + sum_k top_p[t,k] * ff_rows[row_of[t,k]]
__global__ __launch_bounds__(256) void combine_kernel(
    const float* __restrict__ x1, const float* __restrict__ ff_rows,
    const int* __restrict__ row_of, const float* __restrict__ top_p,
    float* __restrict__ out) {
  int t = blockIdx.x;
  int tid = threadIdx.x;
  float4 r = ((const float4*)(x1 + (size_t)t * CD))[tid];
#pragma unroll
  for (int s = 0; s < CK; ++s) {
    float w = top_p[t * 2 + s];
    int row = row_of[t * 2 + s];
    float4 f = ((const float4*)(ff_rows + (size_t)row * CD))[tid];
    r.x += w * f.x; r.y += w * f.y; r.z += w * f.z; r.w += w * f.w;
  }
  ((float4*)(out + (size_t)t * CD))[tid] = r;
}

// ---------------------------------------------------------------------------
extern "C" void kernel_launch(void* const* d_in, const int* in_sizes, int n_in,
                              void* d_out, int out_size, void* d_ws,
                              size_t ws_size, hipStream_t stream) {
  const float* x   = (const float*)d_in[0];
  const float* n1w = (const float*)d_in[1];
  const float* n2w = (const float*)d_in[2];
  const float* wq  = (const float*)d_in[3];
  const float* bq  = (const float*)d_in[4];
  const float* wk  = (const float*)d_in[5];
  const float* bk  = (const float*)d_in[6];
  const float* wv  = (const float*)d_in[7];
  const float* bv  = (const float*)d_in[8];
  const float* wo  = (const float*)d_in[9];
  const float* bo  = (const float*)d_in[10];
  const float* wr  = (const float*)d_in[11];
  const float* br  = (const float*)d_in[12];
  const float* w1  = (const float*)d_in[13];
  const float* b1  = (const float*)d_in[14];
  const float* w2  = (const float*)d_in[15];
  const float* b2  = (const float*)d_in[16];
  float* out = (float*)d_out;

  char* base = (char*)d_ws;
  size_t off = 0;
  auto alloc = [&](size_t bytes) -> void* {
    void* p = base + off;
    off += (bytes + 255) & ~(size_t)255;
    return p;
  };
  float* f_x1   = (float*)alloc((size_t)CT * CD * 4);
  float* f_h2   = (float*)alloc((size_t)CT * CD * 4);
  short* f_xg   = (short*)alloc((size_t)MAXROWS * CD * 2);
  short* f_hid  = (short*)alloc((size_t)MAXROWS * CF * 2);
  float* f_ff   = (float*)alloc((size_t)MAXROWS * CD * 4);
  short* f_hh   = (short*)alloc((size_t)CT * CD * 2);
  short* f_hl   = (short*)alloc((size_t)CT * CD * 2);
  short* f_wqkvh = (short*)alloc((size_t)QKVP * CD * 2);
  short* f_wqkvl = (short*)alloc((size_t)QKVP * CD * 2);
  float* f_qkv  = (float*)alloc((size_t)CT * QKVP * 4);
  short* f_ctxh = (short*)alloc((size_t)CT * CD * 2);
  short* f_ctxl = (short*)alloc((size_t)CT * CD * 2);
  short* f_woth = (short*)alloc((size_t)CD * CD * 2);
  short* f_wotl = (short*)alloc((size_t)CD * CD * 2);
  float* f_bqkv = (float*)alloc(QKVP * 4);
  float* f_topp = (float*)alloc(CT * CK * 4);
  float* f_probs = (float*)alloc(CT * CE * 4);
  int* i_topi   = (int*)alloc(CT * CK * 4);
  int* i_rowof  = (int*)alloc(CT * CK * 4);
  int* i_rowmap = (int*)alloc(MAXROWS * 4);
  int* i_cursor = (int*)alloc(CE * 4);
  int* i_offs   = (int*)alloc((CE + 1) * 4);
  int* i_tile   = (int*)alloc(MAXTILES * 4);
  int* i_total  = (int*)alloc(4);
  // G (64MB): w1t -> w2t (sequential reuse)
  short* f_wG = (short*)alloc((size_t)CE * CD * CF * 2);
  short* f_w1t = f_wG;
  short* f_w2t = f_wG;
  // Rs (48MB): QKV partials -> WO partials -> GEMM2 partials (disjoint)
  void* Rs = alloc((size_t)4 * MAXROWS * CD * 4);
  float* f_partqkv = (float*)Rs;
  float* f_partwo = (float*)Rs;
  float* f_partg2 = (float*)Rs;

  dim3 b256(256);

  zero_kernel<<<1, 64, 0, stream>>>(i_cursor);
  pack_bias_kernel<<<QKVP / 256, b256, 0, stream>>>(bq, bk, bv, f_bqkv);
  // weight preprocessing (hi/lo for attention, hi-only for experts)
  transpose_convert_kernel<<<dim3(16, 16, 1), b256, 0, stream>>>(
      wq, f_wqkvh + 0 * (size_t)CD * CD, f_wqkvl + 0 * (size_t)CD * CD, CD, CD);
  transpose_convert_kernel<<<dim3(16, 16, 1), b256, 0, stream>>>(
      wk, f_wqkvh + 1 * (size_t)CD * CD, f_wqkvl + 1 * (size_t)CD * CD, CD, CD);
  transpose_convert_kernel<<<dim3(16, 16, 1), b256, 0, stream>>>(
      wv, f_wqkvh + 2 * (size_t)CD * CD, f_wqkvl + 2 * (size_t)CD * CD, CD, CD);
  transpose_convert_kernel<<<dim3(16, 16, 1), b256, 0, stream>>>(
      wo, f_woth, f_wotl, CD, CD);
  transpose_convert_kernel<<<dim3(CF / 64, CD / 64, CE), b256, 0, stream>>>(
      w1, f_w1t, nullptr, CD, CF);

  // ---- attention ----
  rmsnorm_kernel<2><<<CT, b256, 0, stream>>>(x, n1w, f_hh, f_hl);
  mfma_gemm_kernel<1><<<dim3(QKVP / 128, CT / 128, 2), b256, 0, stream>>>(
      f_hh, f_hl, f_wqkvh, f_wqkvl, f_partqkv, CT, QKVP, CD);
  reduce_splitk_kernel<<<CT, b256, 0, stream>>>(f_partqkv, CT, 2, f_bqkv,
                                                nullptr, nullptr, f_qkv, QKVP,
                                                nullptr);
  fused_attn_kernel<<<dim3(CS / 16, CBH), b256, 0, stream>>>(f_qkv, f_ctxh,
                                                             f_ctxl);
  mfma_gemm_kernel<1><<<dim3(CD / 128, CT / 128, 4), b256, 0, stream>>>(
      f_ctxh, f_ctxl, f_woth, f_wotl, f_partwo, CT, CD, CD);
  reduce_splitk_kernel<<<CT, b256, 0, stream>>>(f_partwo, CT, 4, bo, nullptr, x,
                                                f_x1, CD, nullptr);

  // ---- MoE ----
  rmsnorm_kernel<0><<<CT, b256, 0, stream>>>(f_x1, n2w, f_h2, nullptr);
  router_kernel<<<CT, dim3(64), 0, stream>>>(f_h2, wr, br, i_topi, f_topp,
                                             f_probs);
  finalize_kernel<<<1, 256, 0, stream>>>(i_topi, f_probs, i_offs, i_tile,
                                         i_total, i_rowmap,
                                         out + (size_t)CT * CD);
  gather_kernel<<<(CT * CK + 255) / 256, b256, 0, stream>>>(i_topi, i_offs,
                                                            i_cursor, i_rowmap,
                                                            i_rowof);
  gatherx_kernel<<<MAXROWS, b256, 0, stream>>>(f_h2, i_rowmap, f_xg);

  moe_gemm_kernel<1, 1><<<dim3(CF / 256, MAXTILES, 1), dim3(512), 0, stream>>>(
      f_xg, f_w1t, b1, f_hid, nullptr, 0, CF, CD, i_tile, i_total);
  transpose_convert_kernel<<<dim3(CD / 64, CF / 64, CE), b256, 0, stream>>>(
      w2, f_w2t, nullptr, CF, CD);
  moe_gemm_kernel<0, 0><<<dim3(CD / 256, MAXTILES, 4), dim3(512), 0, stream>>>(
      f_hid, f_w2t, nullptr, nullptr, f_partg2, MAXROWS, CD, CF, i_tile,
      i_total);
  reduce_splitk_kernel<<<MAXROWS, b256, 0, stream>>>(f_partg2, MAXROWS, 4, b2,
                                                     i_tile, nullptr, f_ff, CD,
                                                     i_total);

  combine_kernel<<<CT, b256, 0, stream>>>(f_x1, f_ff, i_rowof, f_topp, out);
}

// Round 11
// 372.263 us; speedup vs baseline: 1.2612x; 1.0826x over previous
//
#include <hip/hip_runtime.h>
#include <math.h>

// Problem constants
#define CB 2
#define CS 512
#define CD 1024
#define CH 16
#define CHD 64
#define CF 4096
#define CE 8
#define CK 2
#define CT (CB*CS)      // 1024 tokens
#define CBH (CB*CH)     // 32 (batch*heads)
#define CEPS 1e-6f
#define QKVP 3072       // packed q|k|v row pitch
#define MAXROWS 3072    // 2048 + 8*127 padded to 128
#define MAXTILES (MAXROWS/128)

typedef __attribute__((ext_vector_type(8))) short bf16x8;
typedef __attribute__((ext_vector_type(4))) float f32x4;

__device__ __forceinline__ short f2bf(float f) {
  unsigned u = __float_as_uint(f);
  unsigned r = (u + 0x7FFF + ((u >> 16) & 1)) >> 16;
  return (short)r;
}
__device__ __forceinline__ float bf2f(short h) {
  return __uint_as_float(((unsigned)(unsigned short)h) << 16);
}

__device__ __forceinline__ void gload_lds16(const void* g, void* l) {
  __builtin_amdgcn_global_load_lds(
      (const __attribute__((address_space(1))) unsigned int*)g,
      (__attribute__((address_space(3))) unsigned int*)l, 16, 0, 0);
}

// ---------------------------------------------------------------------------
// RMSNorm. MODE 0: fp32 out (outA). MODE 2: hi/lo bf16 planes (outA=hi, outB=lo)
template <int MODE>
__global__ __launch_bounds__(256) void rmsnorm_kernel(
    const float* __restrict__ x, const float* __restrict__ w,
    void* __restrict__ outA, void* __restrict__ outB) {
  int t = blockIdx.x;
  int tid = threadIdx.x;
  float4 xv = ((const float4*)(x + (size_t)t * CD))[tid];
  float ss = xv.x*xv.x + xv.y*xv.y + xv.z*xv.z + xv.w*xv.w;
  for (int off = 32; off > 0; off >>= 1) ss += __shfl_down(ss, off);
  __shared__ float red[4];
  __shared__ float s_scale;
  int lane = tid & 63, wid = tid >> 6;
  if (lane == 0) red[wid] = ss;
  __syncthreads();
  if (tid == 0) {
    float tot = red[0] + red[1] + red[2] + red[3];
    s_scale = rsqrtf(tot / (float)CD + CEPS);
  }
  __syncthreads();
  float sc = s_scale;
  float4 wv = ((const float4*)w)[tid];
  float o[4] = {xv.x * sc * wv.x, xv.y * sc * wv.y,
                xv.z * sc * wv.z, xv.w * sc * wv.w};
  if (MODE == 0) {
    ((float4*)((float*)outA + (size_t)t * CD))[tid] =
        make_float4(o[0], o[1], o[2], o[3]);
  } else {
    short4 hi, lo;
    short* hp = (short*)&hi; short* lp = (short*)&lo;
#pragma unroll
    for (int i = 0; i < 4; ++i) {
      short h = f2bf(o[i]);
      hp[i] = h;
      lp[i] = f2bf(o[i] - bf2f(h));
    }
    ((short4*)((short*)outA + (size_t)t * CD))[tid] = hi;
    ((short4*)((short*)outB + (size_t)t * CD))[tid] = lo;
  }
}

// ---------------------------------------------------------------------------
// Tiled transpose+convert, 64x64 tile, 16B short8 stores:
// W[e][Kd][Nd] f32 -> Wth[e][Nd][Kd] bf16 (+ optional lo plane).
__global__ __launch_bounds__(256) void transpose_convert_kernel(
    const float* __restrict__ W, short* __restrict__ Wth,
    short* __restrict__ Wtl, int Kd, int Nd) {
  int e = blockIdx.z;
  const float* Wb = W + (size_t)e * Kd * Nd;
  size_t obase = (size_t)e * Kd * Nd;
  int n0 = blockIdx.x * 64, k0 = blockIdx.y * 64;
  __shared__ float t[64][65];
  int tid = threadIdx.x;
#pragma unroll
  for (int i = 0; i < 4; ++i) {
    int idx = i * 256 + tid;
    int r = idx >> 4, c4 = (idx & 15) * 4;
    float4 v = *(const float4*)(Wb + (size_t)(k0 + r) * Nd + n0 + c4);
    t[r][c4] = v.x; t[r][c4 + 1] = v.y; t[r][c4 + 2] = v.z; t[r][c4 + 3] = v.w;
  }
  __syncthreads();
  int n = tid >> 2, k16 = (tid & 3) * 16;
  short th[16], tl[16];
#pragma unroll
  for (int j = 0; j < 16; ++j) {
    float v = t[k16 + j][n];
    short hi = f2bf(v);
    th[j] = hi;
    tl[j] = f2bf(v - bf2f(hi));
  }
  size_t oo = obase + (size_t)(n0 + n) * Kd + k0 + k16;
  ((int4*)(Wth + oo))[0] = ((int4*)th)[0];
  ((int4*)(Wth + oo + 8))[0] = ((int4*)th)[1];
  if (Wtl) {
    ((int4*)(Wtl + oo))[0] = ((int4*)tl)[0];
    ((int4*)(Wtl + oo + 8))[0] = ((int4*)tl)[1];
  }
}

__global__ void pack_bias_kernel(const float* __restrict__ bq,
                                 const float* __restrict__ bk,
                                 const float* __restrict__ bv,
                                 float* __restrict__ out) {
  int i = blockIdx.x * 256 + threadIdx.x;
  if (i < QKVP)
    out[i] = (i < 1024) ? bq[i] : (i < 2048 ? bk[i - 1024] : bv[i - 2048]);
}

// ---------------------------------------------------------------------------
// MoE grouped GEMM: BM=128, BN=256, BK=64, 8 waves.
template <int SILU, int OUTBF>
__global__ __launch_bounds__(512) void moe_gemm_kernel(
    const short* __restrict__ A, const short* __restrict__ Bt,
    const float* __restrict__ bias, void* __restrict__ Cout,
    float* __restrict__ part, int partM, int N, int K,
    const int* __restrict__ tile_e, const int* __restrict__ total_rows) {
  __shared__ __align__(16) short A0[128 * 64], A1[128 * 64];
  __shared__ __align__(16) short B0[256 * 64], B1[256 * 64];
  int tid = threadIdx.x;
  int m0 = blockIdx.y * 128, n0 = blockIdx.x * 256;
  if (m0 >= *total_rows) return;
  int e = tile_e[blockIdx.y];
  const short* Bb = Bt + (size_t)e * N * K;
  const float* biasb = bias ? bias + (size_t)e * N : nullptr;
  int kz = blockIdx.z;
  int kchunk = K / gridDim.z;
  int kbeg = kz * kchunk;
  int nsteps = kchunk >> 6;
  int lane = tid & 63, w = tid >> 6;
  int wr = w >> 2, wc = w & 3;
  int l15 = lane & 15, l4 = lane >> 4;
  f32x4 acc[4][4] = {};

#define STAGE(AS_, BS_, KK)                                                   \
  {                                                                           \
    _Pragma("unroll") for (int i = 0; i < 2; ++i) {                           \
      int c = i * 512 + tid;                                                  \
      int r = c >> 3, gs = c & 7;                                             \
      int g = gs ^ (r & 7);                                                   \
      gload_lds16(A + (size_t)(m0 + r) * K + (KK) + g * 8, &AS_[c * 8]);      \
    }                                                                         \
    _Pragma("unroll") for (int i = 0; i < 4; ++i) {                           \
      int c = i * 512 + tid;                                                  \
      int r = c >> 3, gs = c & 7;                                             \
      int g = gs ^ (r & 7);                                                   \
      gload_lds16(Bb + (size_t)(n0 + r) * K + (KK) + g * 8, &BS_[c * 8]);     \
    }                                                                         \
  }

#define COMPUTE(AS_, BS_)                                                     \
  {                                                                           \
    _Pragma("unroll") for (int ks = 0; ks < 2; ++ks) {                        \
      bf16x8 a[4], b[4];                                                      \
      _Pragma("unroll") for (int m = 0; m < 4; ++m) {                         \
        int row = wr * 64 + m * 16 + l15;                                     \
        int slot = (ks * 4 + l4) ^ (row & 7);                                 \
        a[m] = *(const bf16x8*)&AS_[(row * 8 + slot) * 8];                    \
      }                                                                       \
      _Pragma("unroll") for (int n = 0; n < 4; ++n) {                         \
        int row = wc * 64 + n * 16 + l15;                                     \
        int slot = (ks * 4 + l4) ^ (row & 7);                                 \
        b[n] = *(const bf16x8*)&BS_[(row * 8 + slot) * 8];                    \
      }                                                                       \
      _Pragma("unroll") for (int m = 0; m < 4; ++m)                           \
      _Pragma("unroll") for (int n = 0; n < 4; ++n)                           \
        acc[m][n] = __builtin_amdgcn_mfma_f32_16x16x32_bf16(a[m], b[n],       \
                                                            acc[m][n], 0, 0, 0); \
    }                                                                         \
  }

  STAGE(A0, B0, kbeg);
  __syncthreads();
  for (int s = 0; s < nsteps; s += 2) {
    int k0 = kbeg + (s << 6);
    bool has1 = (s + 1 < nsteps), has2 = (s + 2 < nsteps);
    if (has1) STAGE(A1, B1, k0 + 64);
    COMPUTE(A0, B0);
    __syncthreads();
    if (has1) {
      if (has2) STAGE(A0, B0, k0 + 128);
      COMPUTE(A1, B1);
      __syncthreads();
    }
  }
#undef STAGE
#undef COMPUTE

  if (gridDim.z > 1) {
#pragma unroll
    for (int m = 0; m < 4; ++m) {
      int row = m0 + wr * 64 + m * 16 + l4 * 4;
#pragma unroll
      for (int n = 0; n < 4; ++n) {
        int col = n0 + wc * 64 + n * 16 + l15;
#pragma unroll
        for (int q = 0; q < 4; ++q)
          part[((size_t)kz * partM + row + q) * N + col] = acc[m][n][q];
      }
    }
    return;
  }
  float* outf = (float*)Cout;
  short* outb = (short*)Cout;
#pragma unroll
  for (int m = 0; m < 4; ++m) {
    int row = m0 + wr * 64 + m * 16 + l4 * 4;
#pragma unroll
    for (int n = 0; n < 4; ++n) {
      int col = n0 + wc * 64 + n * 16 + l15;
      float bv = biasb[col];
#pragma unroll
      for (int q = 0; q < 4; ++q) {
        float v = acc[m][n][q] + bv;
        if (SILU) v = v / (1.f + __expf(-v));
        if (OUTBF) outb[(size_t)(row + q) * N + col] = f2bf(v);
        else outf[(size_t)(row + q) * N + col] = v;
      }
    }
  }
}

// ---------------------------------------------------------------------------
// Attention MFMA GEMM: 128x128, BK=32, 4 waves, hi/lo reg-staged, split-K.
template <int LO>
__global__ __launch_bounds__(256) void mfma_gemm_kernel(
    const short* __restrict__ Ah, const short* __restrict__ Al,
    const short* __restrict__ Bh, const short* __restrict__ Bl,
    float* __restrict__ part, int partM, int N, int K) {
  __shared__ short As0[4096], Bs0[4096], As1[4096], Bs1[4096];
  __shared__ short Als0[LO ? 4096 : 64], Bls0[LO ? 4096 : 64];
  __shared__ short Als1[LO ? 4096 : 64], Bls1[LO ? 4096 : 64];
  int tid = threadIdx.x;
  int m0 = blockIdx.y * 128, n0 = blockIdx.x * 128;
  int kz = blockIdx.z;
  int kchunk = K / gridDim.z;
  int kbeg = kz * kchunk;
  int nsteps = kchunk >> 5;
  int lane = tid & 63, w = tid >> 6;
  int wr = w >> 1, wc = w & 1;
  int l15 = lane & 15, l4 = lane >> 4;
  int xorl = (l15 & 3) ^ ((l15 >> 2) & 3);
  f32x4 acc[4][4] = {};
  bf16x8 vA0[2], vB0[2], vAl0[2], vBl0[2];
  bf16x8 vA1[2], vB1[2], vAl1[2], vBl1[2];

#define LOAD_SET(VA, VB, VAL, VBL, KK)                                        \
  {                                                                           \
    _Pragma("unroll") for (int ic = 0; ic < 2; ++ic) {                        \
      int c = ic * 256 + tid;                                                 \
      int r = c >> 2, g = c & 3;                                              \
      size_t ao = (size_t)(m0 + r) * K + (KK) + g * 8;                        \
      size_t bo = (size_t)(n0 + r) * K + (KK) + g * 8;                        \
      VA[ic] = *(const bf16x8*)(Ah + ao);                                     \
      VB[ic] = *(const bf16x8*)(Bh + bo);                                     \
      if (LO) {                                                               \
        VAL[ic] = *(const bf16x8*)(Al + ao);                                  \
        VBL[ic] = *(const bf16x8*)(Bl + bo);                                  \
      }                                                                       \
    }                                                                         \
  }

#define WRITE_SET(AS_, BS_, ALS_, BLS_, VA, VB, VAL, VBL)                     \
  {                                                                           \
    _Pragma("unroll") for (int ic = 0; ic < 2; ++ic) {                        \
      int c = ic * 256 + tid;                                                 \
      int r = c >> 2, g = c & 3;                                              \
      int ch = (r * 4 + (g ^ (r & 3) ^ ((r >> 2) & 3))) * 8;                  \
      *(bf16x8*)&AS_[ch] = VA[ic];                                            \
      *(bf16x8*)&BS_[ch] = VB[ic];                                            \
      if (LO) {                                                               \
        *(bf16x8*)&ALS_[ch] = VAL[ic];                                        \
        *(bf16x8*)&BLS_[ch] = VBL[ic];                                        \
      }                                                                       \
    }                                                                         \
  }

#define COMPUTE_SET(AS_, BS_, ALS_, BLS_)                                     \
  {                                                                           \
    bf16x8 ah[4], al[4];                                                      \
    _Pragma("unroll") for (int m = 0; m < 4; ++m) {                           \
      int row = wr * 64 + m * 16 + l15;                                       \
      int idx = (row * 4 + (l4 ^ xorl)) * 8;                                  \
      ah[m] = *(const bf16x8*)&AS_[idx];                                      \
      if (LO) al[m] = *(const bf16x8*)&ALS_[idx];                             \
    }                                                                         \
    _Pragma("unroll") for (int n = 0; n < 4; ++n) {                           \
      int row = wc * 64 + n * 16 + l15;                                       \
      int idx = (row * 4 + (l4 ^ xorl)) * 8;                                  \
      bf16x8 bhn = *(const bf16x8*)&BS_[idx];                                 \
      bf16x8 bln;                                                             \
      if (LO) bln = *(const bf16x8*)&BLS_[idx];                               \
      _Pragma("unroll") for (int m = 0; m < 4; ++m) {                         \
        acc[m][n] = __builtin_amdgcn_mfma_f32_16x16x32_bf16(ah[m], bhn,       \
                                                            acc[m][n], 0, 0, 0); \
        if (LO) {                                                             \
          acc[m][n] = __builtin_amdgcn_mfma_f32_16x16x32_bf16(al[m], bhn,     \
                                                              acc[m][n], 0, 0, 0); \
          acc[m][n] = __builtin_amdgcn_mfma_f32_16x16x32_bf16(ah[m], bln,     \
                                                              acc[m][n], 0, 0, 0); \
        }                                                                     \
      }                                                                       \
    }                                                                         \
  }

  LOAD_SET(vA0, vB0, vAl0, vBl0, kbeg);
  WRITE_SET(As0, Bs0, Als0, Bls0, vA0, vB0, vAl0, vBl0);
  __syncthreads();
  for (int s = 0; s < nsteps; s += 2) {
    int k0 = kbeg + (s << 5);
    bool has1 = (s + 1 < nsteps), has2 = (s + 2 < nsteps);
    if (has1) LOAD_SET(vA1, vB1, vAl1, vBl1, k0 + 32);
    COMPUTE_SET(As0, Bs0, Als0, Bls0);
    if (has1) WRITE_SET(As1, Bs1, Als1, Bls1, vA1, vB1, vAl1, vBl1);
    __syncthreads();
    if (has1) {
      if (has2) LOAD_SET(vA0, vB0, vAl0, vBl0, k0 + 64);
      COMPUTE_SET(As1, Bs1, Als1, Bls1);
      if (has2) WRITE_SET(As0, Bs0, Als0, Bls0, vA0, vB0, vAl0, vBl0);
      __syncthreads();
    }
  }
#undef LOAD_SET
#undef WRITE_SET
#undef COMPUTE_SET

#pragma unroll
  for (int m = 0; m < 4; ++m) {
    int row = m0 + wr * 64 + m * 16 + l4 * 4;
#pragma unroll
    for (int n = 0; n < 4; ++n) {
      int col = n0 + wc * 64 + n * 16 + l15;
#pragma unroll
      for (int q = 0; q < 4; ++q)
        part[((size_t)kz * partM + row + q) * N + col] = acc[m][n][q];
    }
  }
}

// split-K reduce: out[row][c] = sum_z part[z][row][c] + bias (+res). fp32 out.
__global__ __launch_bounds__(256) void reduce_splitk_kernel(
    const float* __restrict__ part, int partM, int nz,
    const float* __restrict__ bias, const int* __restrict__ tile_e,
    const float* __restrict__ res, float* __restrict__ outp, int N,
    const int* __restrict__ total_rows) {
  int row = blockIdx.x;
  if (total_rows && row >= *total_rows) return;
  const float* bb = bias;
  if (tile_e) bb = bias + (size_t)tile_e[row >> 7] * N;
  for (int c = threadIdx.x * 4; c < N; c += 1024) {
    float4 s = *(const float4*)(part + (size_t)row * N + c);
    for (int z = 1; z < nz; ++z) {
      float4 p = *(const float4*)(part + ((size_t)z * partM + row) * N + c);
      s.x += p.x; s.y += p.y; s.z += p.z; s.w += p.w;
    }
    s.x += bb[c]; s.y += bb[c + 1]; s.z += bb[c + 2]; s.w += bb[c + 3];
    if (res) {
      float4 r = *(const float4*)(res + (size_t)row * N + c);
      s.x += r.x; s.y += r.y; s.z += r.z; s.w += r.w;
    }
    *(float4*)(outp + (size_t)row * N + c) = s;
  }
}

// ---------------------------------------------------------------------------
// Fused attention v3 (flash-style online softmax): 32 q-rows x one (b,h) per
// block, 256 threads. Per thread: rows rg*4..+3 (rg=tid>>5, half-wave group),
// k-cols 2*cg..+1 / d-cols cg,cg+32 (cg=tid&31). No full-S buffer: per-tile
// Pt[32][66] only -> LDS 51.2KB, 3 blocks/CU. K row-major stride 65 (bank
// c+d: 2-way on staging writes AND column reads). m/l/O state in registers;
// row-reduce via __shfl_xor<=16 (stays in half-wave). fp32 throughout.
__global__ __launch_bounds__(256) void fused_attn_kernel(
    const float* __restrict__ qkv, short* __restrict__ ctxh,
    short* __restrict__ ctxl) {
  __shared__ float Qs[32][68];   // Q tile (float4-staged)
  __shared__ float Ks[64 * 65];  // K row-major, stride 65
  __shared__ float Vs[64][68];   // V row-major
  __shared__ float Pt[32][66];   // per-tile P
  int qt = blockIdx.x, bh = blockIdx.y;
  int b = bh / CH, h = bh % CH;
  int qrow0 = qt * 32;
  int ktmax = (qrow0 + 31) >> 6;
  int tid = threadIdx.x;
  int cg = tid & 31, rg = tid >> 5;
  int r0 = rg * 4;

  // stage Q [32][64]
#pragma unroll
  for (int it = 0; it < 2; ++it) {
    int idx = it * 256 + tid;
    int r = idx >> 4, c4 = (idx & 15) * 4;
    *(float4*)&Qs[r][c4] = *(const float4*)(
        qkv + (size_t)(b * CS + qrow0 + r) * QKVP + h * CHD + c4);
  }

  float m_i[4], l_i[4], O[4][2];
#pragma unroll
  for (int i = 0; i < 4; ++i) {
    m_i[i] = -1e30f;
    l_i[i] = 0.f;
    O[i][0] = 0.f;
    O[i][1] = 0.f;
  }

  for (int kt = 0; kt <= ktmax; ++kt) {
    __syncthreads();  // prev tile's Pt/Vs reads done before overwrite
    // stage K (scalar, stride 65) and V (float4, stride 68)
#pragma unroll
    for (int it = 0; it < 4; ++it) {
      int idx = it * 256 + tid;
      int r = idx >> 4, c4 = (idx & 15) * 4;
      const float* src =
          qkv + (size_t)(b * CS + kt * 64 + r) * QKVP + h * CHD;
      float4 kv = *(const float4*)(src + 1024 + c4);
      Ks[r * 65 + c4 + 0] = kv.x;
      Ks[r * 65 + c4 + 1] = kv.y;
      Ks[r * 65 + c4 + 2] = kv.z;
      Ks[r * 65 + c4 + 3] = kv.w;
      *(float4*)&Vs[r][c4] = *(const float4*)(src + 2048 + c4);
    }
    __syncthreads();

    // scores: s[4 rows][2 cols]
    float s[4][2] = {};
#pragma unroll 4
    for (int d = 0; d < 64; ++d) {
      float q0 = Qs[r0 + 0][d];
      float q1 = Qs[r0 + 1][d];
      float q2 = Qs[r0 + 2][d];
      float q3 = Qs[r0 + 3][d];
      float k0 = Ks[(cg * 2 + 0) * 65 + d];
      float k1 = Ks[(cg * 2 + 1) * 65 + d];
      s[0][0] += q0 * k0; s[0][1] += q0 * k1;
      s[1][0] += q1 * k0; s[1][1] += q1 * k1;
      s[2][0] += q2 * k0; s[2][1] += q2 * k1;
      s[3][0] += q3 * k0; s[3][1] += q3 * k1;
    }

    // online softmax update (per row, reduce over 32-lane col group)
#pragma unroll
    for (int i = 0; i < 4; ++i) {
      int gr = qrow0 + r0 + i;
      int gc0 = kt * 64 + cg * 2;
      float s0 = (gc0 + 0 > gr) ? -1e30f : s[i][0] * 0.125f;
      float s1 = (gc0 + 1 > gr) ? -1e30f : s[i][1] * 0.125f;
      float tmax = fmaxf(s0, s1);
#pragma unroll
      for (int off = 16; off > 0; off >>= 1)
        tmax = fmaxf(tmax, __shfl_xor(tmax, off));
      float newm = fmaxf(m_i[i], tmax);
      float p0 = __expf(s0 - newm);
      float p1 = __expf(s1 - newm);
      float tsum = p0 + p1;
#pragma unroll
      for (int off = 16; off > 0; off >>= 1) tsum += __shfl_xor(tsum, off);
      float scale = __expf(m_i[i] - newm);
      l_i[i] = l_i[i] * scale + tsum;
      m_i[i] = newm;
      O[i][0] *= scale;
      O[i][1] *= scale;
      Pt[r0 + i][cg * 2 + 0] = p0;
      Pt[r0 + i][cg * 2 + 1] = p1;
    }
    __syncthreads();

    // PV: O[i][jd] += sum_c Pt[row][c] * V[c][cg + 32*jd]
#pragma unroll 4
    for (int c = 0; c < 64; ++c) {
      float p0 = Pt[r0 + 0][c];
      float p1 = Pt[r0 + 1][c];
      float p2 = Pt[r0 + 2][c];
      float p3 = Pt[r0 + 3][c];
      float v0 = Vs[c][cg];
      float v1 = Vs[c][cg + 32];
      O[0][0] += p0 * v0; O[0][1] += p0 * v1;
      O[1][0] += p1 * v0; O[1][1] += p1 * v1;
      O[2][0] += p2 * v0; O[2][1] += p2 * v1;
      O[3][0] += p3 * v0; O[3][1] += p3 * v1;
    }
  }

  // epilogue: normalize by l, write hi/lo bf16 planes
#pragma unroll
  for (int i = 0; i < 4; ++i) {
    float inv = 1.0f / l_i[i];
#pragma unroll
    for (int jd = 0; jd < 2; ++jd) {
      int dv = cg + 32 * jd;
      size_t oi = (size_t)(b * CS + qrow0 + r0 + i) * CD + h * CHD + dv;
      float v = O[i][jd] * inv;
      short hi = f2bf(v);
      ctxh[oi] = hi;
      ctxl[oi] = f2bf(v - bf2f(hi));
    }
  }
}

// ---------------------------------------------------------------------------
__global__ void zero_kernel(int* cursor) {
  int i = threadIdx.x;
  if (i < CE) cursor[i] = 0;
}

// Router: one WAVE per token (no atomics; stats in finalize).
__global__ __launch_bounds__(64) void router_kernel(
    const float* __restrict__ h2, const float* __restrict__ wr,
    const float* __restrict__ br, int* __restrict__ top_i,
    float* __restrict__ top_p, float* __restrict__ probs_out) {
  int t = blockIdx.x;
  int lane = threadIdx.x;
  float a[CE] = {};
  const float4* hv4 = (const float4*)(h2 + (size_t)t * CD);
#pragma unroll
  for (int i = 0; i < 4; ++i) {
    float4 hv = hv4[lane * 4 + i];
    const float* wrow = wr + (size_t)(lane * 16 + i * 4) * CE;
    float hh[4] = {hv.x, hv.y, hv.z, hv.w};
#pragma unroll
    for (int j = 0; j < 4; ++j)
#pragma unroll
      for (int e = 0; e < CE; ++e) a[e] += hh[j] * wrow[j * CE + e];
  }
#pragma unroll
  for (int e = 0; e < CE; ++e)
    for (int off = 32; off > 0; off >>= 1) a[e] += __shfl_down(a[e], off);
  if (lane == 0) {
    float probs[CE];
    float mx = -1e30f;
#pragma unroll
    for (int e = 0; e < CE; ++e) {
      a[e] += br[e];
      mx = fmaxf(mx, a[e]);
    }
    float sum = 0.f;
#pragma unroll
    for (int e = 0; e < CE; ++e) { probs[e] = __expf(a[e] - mx); sum += probs[e]; }
    float inv = 1.0f / sum;
#pragma unroll
    for (int e = 0; e < CE; ++e) {
      probs[e] *= inv;
      probs_out[t * CE + e] = probs[e];
    }
    int i1 = 0;
#pragma unroll
    for (int e = 1; e < CE; ++e) if (probs[e] > probs[i1]) i1 = e;
    int i2 = (i1 == 0) ? 1 : 0;
#pragma unroll
    for (int e = 0; e < CE; ++e)
      if (e != i1 && probs[e] > probs[i2]) i2 = e;
    float p1 = probs[i1], p2 = probs[i2];
    float s12 = p1 + p2;
    top_i[t * 2 + 0] = i1;
    top_i[t * 2 + 1] = i2;
    top_p[t * 2 + 0] = p1 / s12;
    top_p[t * 2 + 1] = p2 / s12;
  }
}

// Finalize (1 block): deterministic counts/psum, offsets, tile map, aux loss.
__global__ __launch_bounds__(256) void finalize_kernel(
    const int* __restrict__ top_i, const float* __restrict__ probs,
    int* __restrict__ offs, int* __restrict__ tile_e,
    int* __restrict__ total_padded, int* __restrict__ row_map,
    float* __restrict__ aux_out) {
  int tid = threadIdx.x;
  __shared__ float redp[256][CE];
  __shared__ int redc[256][CE];
  float lp[CE] = {};
  int lc[CE] = {};
  for (int t = tid; t < CT; t += 256) {
    lc[top_i[t * 2 + 0]]++;
    lc[top_i[t * 2 + 1]]++;
#pragma unroll
    for (int e = 0; e < CE; ++e) lp[e] += probs[t * CE + e];
  }
#pragma unroll
  for (int e = 0; e < CE; ++e) { redp[tid][e] = lp[e]; redc[tid][e] = lc[e]; }
  __syncthreads();
  for (int s = 128; s > 0; s >>= 1) {
    if (tid < s) {
#pragma unroll
      for (int e = 0; e < CE; ++e) {
        redp[tid][e] += redp[tid + s][e];
        redc[tid][e] += redc[tid + s][e];
      }
    }
    __syncthreads();
  }
  __shared__ int s_off[CE + 1];
  if (tid == 0) {
    int o = 0;
    for (int e = 0; e < CE; ++e) {
      s_off[e] = o;
      offs[e] = o;
      o += ((redc[0][e] + 127) >> 7) << 7;
    }
    s_off[CE] = o;
    offs[CE] = o;
    *total_padded = o;
    int nt = o >> 7;
    for (int i = 0; i < nt; ++i) {
      int e = 0;
      while (e < CE - 1 && i * 128 >= s_off[e + 1]) e++;
      tile_e[i] = e;
    }
    float aux = 0.f;
    for (int e = 0; e < CE; ++e)
      aux += ((float)redc[0][e] / (float)(CT * CK)) * (redp[0][e] / (float)CT);
    aux_out[0] = aux * (float)CE;
  }
  __syncthreads();
  for (int i = tid; i < MAXROWS; i += blockDim.x) row_map[i] = -1;
}

__global__ void gather_kernel(const int* __restrict__ top_i,
                              const int* __restrict__ offs,
                              int* __restrict__ cursor, int* __restrict__ row_map,
                              int* __restrict__ row_of) {
  int idx = blockIdx.x * blockDim.x + threadIdx.x;
  if (idx >= CT * CK) return;
  int e = top_i[idx];
  int pos = offs[e] + atomicAdd(&cursor[e], 1);
  row_map[pos] = idx >> 1;
  row_of[idx] = pos;
}

// Xg[row] = bf16(h2[row_map[row]]) or zeros for pad rows.
__global__ __launch_bounds__(256) void gatherx_kernel(
    const float* __restrict__ h2, const int* __restrict__ row_map,
    short* __restrict__ Xg) {
  int row = blockIdx.x;
  int tid = threadIdx.x;
  int tok = row_map[row];
  short4 o;
  if (tok < 0) {
    o = make_short4(0, 0, 0, 0);
  } else {
    float4 v = ((const float4*)(h2 + (size_t)tok * CD))[tid];
    o = make_short4(f2bf(v.x), f2bf(v.y), f2bf(v.z), f2bf(v.w));
  }
  ((short4*)(Xg + (size_t)row * CD))[tid] = o;
}

// out[t] = x1[t] + sum_k top_p[t,k] * ff_rows[row_of[t,k]]
__global__ __launch_bounds__(256) void combine_kernel(
    const float* __restrict__ x1, const float* __restrict__ ff_rows,
    const int* __restrict__ row_of, const float* __restrict__ top_p,
    float* __restrict__ out) {
  int t = blockIdx.x;
  int tid = threadIdx.x;
  float4 r = ((const float4*)(x1 + (size_t)t * CD))[tid];
#pragma unroll
  for (int s = 0; s < CK; ++s) {
    float w = top_p[t * 2 + s];
    int row = row_of[t * 2 + s];
    float4 f = ((const float4*)(ff_rows + (size_t)row * CD))[tid];
    r.x += w * f.x; r.y += w * f.y; r.z += w * f.z; r.w += w * f.w;
  }
  ((float4*)(out + (size_t)t * CD))[tid] = r;
}

// ---------------------------------------------------------------------------
extern "C" void kernel_launch(void* const* d_in, const int* in_sizes, int n_in,
                              void* d_out, int out_size, void* d_ws,
                              size_t ws_size, hipStream_t stream) {
  const float* x   = (const float*)d_in[0];
  const float* n1w = (const float*)d_in[1];
  const float* n2w = (const float*)d_in[2];
  const float* wq  = (const float*)d_in[3];
  const float* bq  = (const float*)d_in[4];
  const float* wk  = (const float*)d_in[5];
  const float* bk  = (const float*)d_in[6];
  const float* wv  = (const float*)d_in[7];
  const float* bv  = (const float*)d_in[8];
  const float* wo  = (const float*)d_in[9];
  const float* bo  = (const float*)d_in[10];
  const float* wr  = (const float*)d_in[11];
  const float* br  = (const float*)d_in[12];
  const float* w1  = (const float*)d_in[13];
  const float* b1  = (const float*)d_in[14];
  const float* w2  = (const float*)d_in[15];
  const float* b2  = (const float*)d_in[16];
  float* out = (float*)d_out;

  char* base = (char*)d_ws;
  size_t off = 0;
  auto alloc = [&](size_t bytes) -> void* {
    void* p = base + off;
    off += (bytes + 255) & ~(size_t)255;
    return p;
  };
  float* f_x1   = (float*)alloc((size_t)CT * CD * 4);
  float* f_h2   = (float*)alloc((size_t)CT * CD * 4);
  short* f_xg   = (short*)alloc((size_t)MAXROWS * CD * 2);
  short* f_hid  = (short*)alloc((size_t)MAXROWS * CF * 2);
  float* f_ff   = (float*)alloc((size_t)MAXROWS * CD * 4);
  short* f_hh   = (short*)alloc((size_t)CT * CD * 2);
  short* f_hl   = (short*)alloc((size_t)CT * CD * 2);
  short* f_wqkvh = (short*)alloc((size_t)QKVP * CD * 2);
  short* f_wqkvl = (short*)alloc((size_t)QKVP * CD * 2);
  float* f_qkv  = (float*)alloc((size_t)CT * QKVP * 4);
  short* f_ctxh = (short*)alloc((size_t)CT * CD * 2);
  short* f_ctxl = (short*)alloc((size_t)CT * CD * 2);
  short* f_woth = (short*)alloc((size_t)CD * CD * 2);
  short* f_wotl = (short*)alloc((size_t)CD * CD * 2);
  float* f_bqkv = (float*)alloc(QKVP * 4);
  float* f_topp = (float*)alloc(CT * CK * 4);
  float* f_probs = (float*)alloc(CT * CE * 4);
  int* i_topi   = (int*)alloc(CT * CK * 4);
  int* i_rowof  = (int*)alloc(CT * CK * 4);
  int* i_rowmap = (int*)alloc(MAXROWS * 4);
  int* i_cursor = (int*)alloc(CE * 4);
  int* i_offs   = (int*)alloc((CE + 1) * 4);
  int* i_tile   = (int*)alloc(MAXTILES * 4);
  int* i_total  = (int*)alloc(4);
  // G (64MB): w1t -> w2t (sequential reuse)
  short* f_wG = (short*)alloc((size_t)CE * CD * CF * 2);
  short* f_w1t = f_wG;
  short* f_w2t = f_wG;
  // Rs (48MB): QKV partials -> WO partials -> GEMM2 partials (disjoint)
  void* Rs = alloc((size_t)4 * MAXROWS * CD * 4);
  float* f_partqkv = (float*)Rs;
  float* f_partwo = (float*)Rs;
  float* f_partg2 = (float*)Rs;

  dim3 b256(256);

  zero_kernel<<<1, 64, 0, stream>>>(i_cursor);
  pack_bias_kernel<<<QKVP / 256, b256, 0, stream>>>(bq, bk, bv, f_bqkv);
  // weight preprocessing (hi/lo for attention, hi-only for experts)
  transpose_convert_kernel<<<dim3(16, 16, 1), b256, 0, stream>>>(
      wq, f_wqkvh + 0 * (size_t)CD * CD, f_wqkvl + 0 * (size_t)CD * CD, CD, CD);
  transpose_convert_kernel<<<dim3(16, 16, 1), b256, 0, stream>>>(
      wk, f_wqkvh + 1 * (size_t)CD * CD, f_wqkvl + 1 * (size_t)CD * CD, CD, CD);
  transpose_convert_kernel<<<dim3(16, 16, 1), b256, 0, stream>>>(
      wv, f_wqkvh + 2 * (size_t)CD * CD, f_wqkvl + 2 * (size_t)CD * CD, CD, CD);
  transpose_convert_kernel<<<dim3(16, 16, 1), b256, 0, stream>>>(
      wo, f_woth, f_wotl, CD, CD);
  transpose_convert_kernel<<<dim3(CF / 64, CD / 64, CE), b256, 0, stream>>>(
      w1, f_w1t, nullptr, CD, CF);

  // ---- attention ----
  rmsnorm_kernel<2><<<CT, b256, 0, stream>>>(x, n1w, f_hh, f_hl);
  mfma_gemm_kernel<1><<<dim3(QKVP / 128, CT / 128, 2), b256, 0, stream>>>(
      f_hh, f_hl, f_wqkvh, f_wqkvl, f_partqkv, CT, QKVP, CD);
  reduce_splitk_kernel<<<CT, b256, 0, stream>>>(f_partqkv, CT, 2, f_bqkv,
                                                nullptr, nullptr, f_qkv, QKVP,
                                                nullptr);
  fused_attn_kernel<<<dim3(CS / 32, CBH), b256, 0, stream>>>(f_qkv, f_ctxh,
                                                             f_ctxl);
  mfma_gemm_kernel<1><<<dim3(CD / 128, CT / 128, 4), b256, 0, stream>>>(
      f_ctxh, f_ctxl, f_woth, f_wotl, f_partwo, CT, CD, CD);
  reduce_splitk_kernel<<<CT, b256, 0, stream>>>(f_partwo, CT, 4, bo, nullptr, x,
                                                f_x1, CD, nullptr);

  // ---- MoE ----
  rmsnorm_kernel<0><<<CT, b256, 0, stream>>>(f_x1, n2w, f_h2, nullptr);
  router_kernel<<<CT, dim3(64), 0, stream>>>(f_h2, wr, br, i_topi, f_topp,
                                             f_probs);
  finalize_kernel<<<1, 256, 0, stream>>>(i_topi, f_probs, i_offs, i_tile,
                                         i_total, i_rowmap,
                                         out + (size_t)CT * CD);
  gather_kernel<<<(CT * CK + 255) / 256, b256, 0, stream>>>(i_topi, i_offs,
                                                            i_cursor, i_rowmap,
                                                            i_rowof);
  gatherx_kernel<<<MAXROWS, b256, 0, stream>>>(f_h2, i_rowmap, f_xg);

  moe_gemm_kernel<1, 1><<<dim3(CF / 256, MAXTILES, 1), dim3(512), 0, stream>>>(
      f_xg, f_w1t, b1, f_hid, nullptr, 0, CF, CD, i_tile, i_total);
  transpose_convert_kernel<<<dim3(CD / 64, CF / 64, CE), b256, 0, stream>>>(
      w2, f_w2t, nullptr, CF, CD);
  moe_gemm_kernel<0, 0><<<dim3(CD / 256, MAXTILES, 4), dim3(512), 0, stream>>>(
      f_hid, f_w2t, nullptr, nullptr, f_partg2, MAXROWS, CD, CF, i_tile,
      i_total);
  reduce_splitk_kernel<<<MAXROWS, b256, 0, stream>>>(f_partg2, MAXROWS, 4, b2,
                                                     i_tile, nullptr, f_ff, CD,
                                                     i_total);

  combine_kernel<<<CT, b256, 0, stream>>>(f_x1, f_ff, i_rowof, f_topp, out);
}

// Round 12
// 350.342 us; speedup vs baseline: 1.3401x; 1.0626x over previous
//
#include <hip/hip_runtime.h>
#include <math.h>

// Problem constants
#define CB 2
#define CS 512
#define CD 1024
#define CH 16
#define CHD 64
#define CF 4096
#define CE 8
#define CK 2
#define CT (CB*CS)      // 1024 tokens
#define CBH (CB*CH)     // 32 (batch*heads)
#define CEPS 1e-6f
#define QKVP 3072       // packed q|k|v row pitch
#define MAXROWS 3072    // 2048 + 8*127 padded to 128
#define MAXTILES (MAXROWS/128)

typedef __attribute__((ext_vector_type(8))) short bf16x8;
typedef __attribute__((ext_vector_type(4))) float f32x4;

__device__ __forceinline__ short f2bf(float f) {
  unsigned u = __float_as_uint(f);
  unsigned r = (u + 0x7FFF + ((u >> 16) & 1)) >> 16;
  return (short)r;
}
__device__ __forceinline__ float bf2f(short h) {
  return __uint_as_float(((unsigned)(unsigned short)h) << 16);
}

__device__ __forceinline__ void gload_lds16(const void* g, void* l) {
  __builtin_amdgcn_global_load_lds(
      (const __attribute__((address_space(1))) unsigned int*)g,
      (__attribute__((address_space(3))) unsigned int*)l, 16, 0, 0);
}

// ---------------------------------------------------------------------------
// RMSNorm, hi/lo bf16 planes out.
__global__ __launch_bounds__(256) void rmsnorm_hl_kernel(
    const float* __restrict__ x, const float* __restrict__ w,
    short* __restrict__ outH, short* __restrict__ outL) {
  int t = blockIdx.x;
  int tid = threadIdx.x;
  float4 xv = ((const float4*)(x + (size_t)t * CD))[tid];
  float ss = xv.x*xv.x + xv.y*xv.y + xv.z*xv.z + xv.w*xv.w;
  for (int off = 32; off > 0; off >>= 1) ss += __shfl_down(ss, off);
  __shared__ float red[4];
  __shared__ float s_scale;
  int lane = tid & 63, wid = tid >> 6;
  if (lane == 0) red[wid] = ss;
  __syncthreads();
  if (tid == 0) {
    float tot = red[0] + red[1] + red[2] + red[3];
    s_scale = rsqrtf(tot / (float)CD + CEPS);
  }
  __syncthreads();
  float sc = s_scale;
  float4 wv = ((const float4*)w)[tid];
  float o[4] = {xv.x * sc * wv.x, xv.y * sc * wv.y,
                xv.z * sc * wv.z, xv.w * sc * wv.w};
  short4 hi, lo;
  short* hp = (short*)&hi; short* lp = (short*)&lo;
#pragma unroll
  for (int i = 0; i < 4; ++i) {
    short h = f2bf(o[i]);
    hp[i] = h;
    lp[i] = f2bf(o[i] - bf2f(h));
  }
  ((short4*)(outH + (size_t)t * CD))[tid] = hi;
  ((short4*)(outL + (size_t)t * CD))[tid] = lo;
}

// ---------------------------------------------------------------------------
// Tiled transpose+convert, 64x64 tile, 16B short8 stores:
// W[e][Kd][Nd] f32 -> Wth[e][Nd][Kd] bf16 (+ optional lo plane).
__global__ __launch_bounds__(256) void transpose_convert_kernel(
    const float* __restrict__ W, short* __restrict__ Wth,
    short* __restrict__ Wtl, int Kd, int Nd) {
  int e = blockIdx.z;
  const float* Wb = W + (size_t)e * Kd * Nd;
  size_t obase = (size_t)e * Kd * Nd;
  int n0 = blockIdx.x * 64, k0 = blockIdx.y * 64;
  __shared__ float t[64][65];
  int tid = threadIdx.x;
#pragma unroll
  for (int i = 0; i < 4; ++i) {
    int idx = i * 256 + tid;
    int r = idx >> 4, c4 = (idx & 15) * 4;
    float4 v = *(const float4*)(Wb + (size_t)(k0 + r) * Nd + n0 + c4);
    t[r][c4] = v.x; t[r][c4 + 1] = v.y; t[r][c4 + 2] = v.z; t[r][c4 + 3] = v.w;
  }
  __syncthreads();
  int n = tid >> 2, k16 = (tid & 3) * 16;
  short th[16], tl[16];
#pragma unroll
  for (int j = 0; j < 16; ++j) {
    float v = t[k16 + j][n];
    short hi = f2bf(v);
    th[j] = hi;
    tl[j] = f2bf(v - bf2f(hi));
  }
  size_t oo = obase + (size_t)(n0 + n) * Kd + k0 + k16;
  ((int4*)(Wth + oo))[0] = ((int4*)th)[0];
  ((int4*)(Wth + oo + 8))[0] = ((int4*)th)[1];
  if (Wtl) {
    ((int4*)(Wtl + oo))[0] = ((int4*)tl)[0];
    ((int4*)(Wtl + oo + 8))[0] = ((int4*)tl)[1];
  }
}

// Four DxD transposes (wq,wk,wv,wo) in one launch, z selects.
struct TPtrs {
  const float* w[4];
  short* hh[4];
  short* ll[4];
};
__global__ __launch_bounds__(256) void transpose4_kernel(TPtrs p) {
  int z = blockIdx.z;
  const float* Wb = p.w[z];
  short* Wth = p.hh[z];
  short* Wtl = p.ll[z];
  int n0 = blockIdx.x * 64, k0 = blockIdx.y * 64;
  __shared__ float t[64][65];
  int tid = threadIdx.x;
#pragma unroll
  for (int i = 0; i < 4; ++i) {
    int idx = i * 256 + tid;
    int r = idx >> 4, c4 = (idx & 15) * 4;
    float4 v = *(const float4*)(Wb + (size_t)(k0 + r) * CD + n0 + c4);
    t[r][c4] = v.x; t[r][c4 + 1] = v.y; t[r][c4 + 2] = v.z; t[r][c4 + 3] = v.w;
  }
  __syncthreads();
  int n = tid >> 2, k16 = (tid & 3) * 16;
  short th[16], tl[16];
#pragma unroll
  for (int j = 0; j < 16; ++j) {
    float v = t[k16 + j][n];
    short hi = f2bf(v);
    th[j] = hi;
    tl[j] = f2bf(v - bf2f(hi));
  }
  size_t oo = (size_t)(n0 + n) * CD + k0 + k16;
  ((int4*)(Wth + oo))[0] = ((int4*)th)[0];
  ((int4*)(Wth + oo + 8))[0] = ((int4*)th)[1];
  ((int4*)(Wtl + oo))[0] = ((int4*)tl)[0];
  ((int4*)(Wtl + oo + 8))[0] = ((int4*)tl)[1];
}

__global__ void pack_bias_kernel(const float* __restrict__ bq,
                                 const float* __restrict__ bk,
                                 const float* __restrict__ bv,
                                 float* __restrict__ out) {
  int i = blockIdx.x * 256 + threadIdx.x;
  if (i < QKVP)
    out[i] = (i < 1024) ? bq[i] : (i < 2048 ? bk[i - 1024] : bv[i - 2048]);
}

// ---------------------------------------------------------------------------
// MoE grouped GEMM: BM=128, BN=256, BK=64, 8 waves.
template <int SILU, int OUTBF>
__global__ __launch_bounds__(512) void moe_gemm_kernel(
    const short* __restrict__ A, const short* __restrict__ Bt,
    const float* __restrict__ bias, void* __restrict__ Cout,
    float* __restrict__ part, int partM, int N, int K,
    const int* __restrict__ tile_e, const int* __restrict__ total_rows) {
  __shared__ __align__(16) short A0[128 * 64], A1[128 * 64];
  __shared__ __align__(16) short B0[256 * 64], B1[256 * 64];
  int tid = threadIdx.x;
  int m0 = blockIdx.y * 128, n0 = blockIdx.x * 256;
  if (m0 >= *total_rows) return;
  int e = tile_e[blockIdx.y];
  const short* Bb = Bt + (size_t)e * N * K;
  const float* biasb = bias ? bias + (size_t)e * N : nullptr;
  int kz = blockIdx.z;
  int kchunk = K / gridDim.z;
  int kbeg = kz * kchunk;
  int nsteps = kchunk >> 6;
  int lane = tid & 63, w = tid >> 6;
  int wr = w >> 2, wc = w & 3;
  int l15 = lane & 15, l4 = lane >> 4;
  f32x4 acc[4][4] = {};

#define STAGE(AS_, BS_, KK)                                                   \
  {                                                                           \
    _Pragma("unroll") for (int i = 0; i < 2; ++i) {                           \
      int c = i * 512 + tid;                                                  \
      int r = c >> 3, gs = c & 7;                                             \
      int g = gs ^ (r & 7);                                                   \
      gload_lds16(A + (size_t)(m0 + r) * K + (KK) + g * 8, &AS_[c * 8]);      \
    }                                                                         \
    _Pragma("unroll") for (int i = 0; i < 4; ++i) {                           \
      int c = i * 512 + tid;                                                  \
      int r = c >> 3, gs = c & 7;                                             \
      int g = gs ^ (r & 7);                                                   \
      gload_lds16(Bb + (size_t)(n0 + r) * K + (KK) + g * 8, &BS_[c * 8]);     \
    }                                                                         \
  }

#define COMPUTE(AS_, BS_)                                                     \
  {                                                                           \
    _Pragma("unroll") for (int ks = 0; ks < 2; ++ks) {                        \
      bf16x8 a[4], b[4];                                                      \
      _Pragma("unroll") for (int m = 0; m < 4; ++m) {                         \
        int row = wr * 64 + m * 16 + l15;                                     \
        int slot = (ks * 4 + l4) ^ (row & 7);                                 \
        a[m] = *(const bf16x8*)&AS_[(row * 8 + slot) * 8];                    \
      }                                                                       \
      _Pragma("unroll") for (int n = 0; n < 4; ++n) {                         \
        int row = wc * 64 + n * 16 + l15;                                     \
        int slot = (ks * 4 + l4) ^ (row & 7);                                 \
        b[n] = *(const bf16x8*)&BS_[(row * 8 + slot) * 8];                    \
      }                                                                       \
      _Pragma("unroll") for (int m = 0; m < 4; ++m)                           \
      _Pragma("unroll") for (int n = 0; n < 4; ++n)                           \
        acc[m][n] = __builtin_amdgcn_mfma_f32_16x16x32_bf16(a[m], b[n],       \
                                                            acc[m][n], 0, 0, 0); \
    }                                                                         \
  }

  STAGE(A0, B0, kbeg);
  __syncthreads();
  for (int s = 0; s < nsteps; s += 2) {
    int k0 = kbeg + (s << 6);
    bool has1 = (s + 1 < nsteps), has2 = (s + 2 < nsteps);
    if (has1) STAGE(A1, B1, k0 + 64);
    COMPUTE(A0, B0);
    __syncthreads();
    if (has1) {
      if (has2) STAGE(A0, B0, k0 + 128);
      COMPUTE(A1, B1);
      __syncthreads();
    }
  }
#undef STAGE
#undef COMPUTE

  if (gridDim.z > 1) {
#pragma unroll
    for (int m = 0; m < 4; ++m) {
      int row = m0 + wr * 64 + m * 16 + l4 * 4;
#pragma unroll
      for (int n = 0; n < 4; ++n) {
        int col = n0 + wc * 64 + n * 16 + l15;
#pragma unroll
        for (int q = 0; q < 4; ++q)
          part[((size_t)kz * partM + row + q) * N + col] = acc[m][n][q];
      }
    }
    return;
  }
  float* outf = (float*)Cout;
  short* outb = (short*)Cout;
#pragma unroll
  for (int m = 0; m < 4; ++m) {
    int row = m0 + wr * 64 + m * 16 + l4 * 4;
#pragma unroll
    for (int n = 0; n < 4; ++n) {
      int col = n0 + wc * 64 + n * 16 + l15;
      float bv = biasb[col];
#pragma unroll
      for (int q = 0; q < 4; ++q) {
        float v = acc[m][n][q] + bv;
        if (SILU) v = v / (1.f + __expf(-v));
        if (OUTBF) outb[(size_t)(row + q) * N + col] = f2bf(v);
        else outf[(size_t)(row + q) * N + col] = v;
      }
    }
  }
}

// ---------------------------------------------------------------------------
// Attention MFMA GEMM: 128x128, BK=32, 4 waves, hi/lo reg-staged, split-K.
template <int LO>
__global__ __launch_bounds__(256) void mfma_gemm_kernel(
    const short* __restrict__ Ah, const short* __restrict__ Al,
    const short* __restrict__ Bh, const short* __restrict__ Bl,
    float* __restrict__ part, int partM, int N, int K) {
  __shared__ short As0[4096], Bs0[4096], As1[4096], Bs1[4096];
  __shared__ short Als0[LO ? 4096 : 64], Bls0[LO ? 4096 : 64];
  __shared__ short Als1[LO ? 4096 : 64], Bls1[LO ? 4096 : 64];
  int tid = threadIdx.x;
  int m0 = blockIdx.y * 128, n0 = blockIdx.x * 128;
  int kz = blockIdx.z;
  int kchunk = K / gridDim.z;
  int kbeg = kz * kchunk;
  int nsteps = kchunk >> 5;
  int lane = tid & 63, w = tid >> 6;
  int wr = w >> 1, wc = w & 1;
  int l15 = lane & 15, l4 = lane >> 4;
  int xorl = (l15 & 3) ^ ((l15 >> 2) & 3);
  f32x4 acc[4][4] = {};
  bf16x8 vA0[2], vB0[2], vAl0[2], vBl0[2];
  bf16x8 vA1[2], vB1[2], vAl1[2], vBl1[2];

#define LOAD_SET(VA, VB, VAL, VBL, KK)                                        \
  {                                                                           \
    _Pragma("unroll") for (int ic = 0; ic < 2; ++ic) {                        \
      int c = ic * 256 + tid;                                                 \
      int r = c >> 2, g = c & 3;                                              \
      size_t ao = (size_t)(m0 + r) * K + (KK) + g * 8;                        \
      size_t bo = (size_t)(n0 + r) * K + (KK) + g * 8;                        \
      VA[ic] = *(const bf16x8*)(Ah + ao);                                     \
      VB[ic] = *(const bf16x8*)(Bh + bo);                                     \
      if (LO) {                                                               \
        VAL[ic] = *(const bf16x8*)(Al + ao);                                  \
        VBL[ic] = *(const bf16x8*)(Bl + bo);                                  \
      }                                                                       \
    }                                                                         \
  }

#define WRITE_SET(AS_, BS_, ALS_, BLS_, VA, VB, VAL, VBL)                     \
  {                                                                           \
    _Pragma("unroll") for (int ic = 0; ic < 2; ++ic) {                        \
      int c = ic * 256 + tid;                                                 \
      int r = c >> 2, g = c & 3;                                              \
      int ch = (r * 4 + (g ^ (r & 3) ^ ((r >> 2) & 3))) * 8;                  \
      *(bf16x8*)&AS_[ch] = VA[ic];                                            \
      *(bf16x8*)&BS_[ch] = VB[ic];                                            \
      if (LO) {                                                               \
        *(bf16x8*)&ALS_[ch] = VAL[ic];                                        \
        *(bf16x8*)&BLS_[ch] = VBL[ic];                                        \
      }                                                                       \
    }                                                                         \
  }

#define COMPUTE_SET(AS_, BS_, ALS_, BLS_)                                     \
  {                                                                           \
    bf16x8 ah[4], al[4];                                                      \
    _Pragma("unroll") for (int m = 0; m < 4; ++m) {                           \
      int row = wr * 64 + m * 16 + l15;                                       \
      int idx = (row * 4 + (l4 ^ xorl)) * 8;                                  \
      ah[m] = *(const bf16x8*)&AS_[idx];                                      \
      if (LO) al[m] = *(const bf16x8*)&ALS_[idx];                             \
    }                                                                         \
    _Pragma("unroll") for (int n = 0; n < 4; ++n) {                           \
      int row = wc * 64 + n * 16 + l15;                                       \
      int idx = (row * 4 + (l4 ^ xorl)) * 8;                                  \
      bf16x8 bhn = *(const bf16x8*)&BS_[idx];                                 \
      bf16x8 bln;                                                             \
      if (LO) bln = *(const bf16x8*)&BLS_[idx];                               \
      _Pragma("unroll") for (int m = 0; m < 4; ++m) {                         \
        acc[m][n] = __builtin_amdgcn_mfma_f32_16x16x32_bf16(ah[m], bhn,       \
                                                            acc[m][n], 0, 0, 0); \
        if (LO) {                                                             \
          acc[m][n] = __builtin_amdgcn_mfma_f32_16x16x32_bf16(al[m], bhn,     \
                                                              acc[m][n], 0, 0, 0); \
          acc[m][n] = __builtin_amdgcn_mfma_f32_16x16x32_bf16(ah[m], bln,     \
                                                              acc[m][n], 0, 0, 0); \
        }                                                                     \
      }                                                                       \
    }                                                                         \
  }

  LOAD_SET(vA0, vB0, vAl0, vBl0, kbeg);
  WRITE_SET(As0, Bs0, Als0, Bls0, vA0, vB0, vAl0, vBl0);
  __syncthreads();
  for (int s = 0; s < nsteps; s += 2) {
    int k0 = kbeg + (s << 5);
    bool has1 = (s + 1 < nsteps), has2 = (s + 2 < nsteps);
    if (has1) LOAD_SET(vA1, vB1, vAl1, vBl1, k0 + 32);
    COMPUTE_SET(As0, Bs0, Als0, Bls0);
    if (has1) WRITE_SET(As1, Bs1, Als1, Bls1, vA1, vB1, vAl1, vBl1);
    __syncthreads();
    if (has1) {
      if (has2) LOAD_SET(vA0, vB0, vAl0, vBl0, k0 + 64);
      COMPUTE_SET(As1, Bs1, Als1, Bls1);
      if (has2) WRITE_SET(As0, Bs0, Als0, Bls0, vA0, vB0, vAl0, vBl0);
      __syncthreads();
    }
  }
#undef LOAD_SET
#undef WRITE_SET
#undef COMPUTE_SET

#pragma unroll
  for (int m = 0; m < 4; ++m) {
    int row = m0 + wr * 64 + m * 16 + l4 * 4;
#pragma unroll
    for (int n = 0; n < 4; ++n) {
      int col = n0 + wc * 64 + n * 16 + l15;
#pragma unroll
      for (int q = 0; q < 4; ++q)
        part[((size_t)kz * partM + row + q) * N + col] = acc[m][n][q];
    }
  }
}

// split-K reduce (QKV): out[row][c] = sum_z part[z][row][c] + bias. fp32 out.
__global__ __launch_bounds__(256) void reduce_splitk_kernel(
    const float* __restrict__ part, int partM, int nz,
    const float* __restrict__ bias, float* __restrict__ outp, int N) {
  int row = blockIdx.x;
  for (int c = threadIdx.x * 4; c < N; c += 1024) {
    float4 s = *(const float4*)(part + (size_t)row * N + c);
    for (int z = 1; z < nz; ++z) {
      float4 p = *(const float4*)(part + ((size_t)z * partM + row) * N + c);
      s.x += p.x; s.y += p.y; s.z += p.z; s.w += p.w;
    }
    s.x += bias[c]; s.y += bias[c + 1]; s.z += bias[c + 2]; s.w += bias[c + 3];
    *(float4*)(outp + (size_t)row * N + c) = s;
  }
}

// ---------------------------------------------------------------------------
// Attention epilogue (fused): WO split-K reduce + residual + rmsnorm2 + router.
// One block per token, 256 threads (thread -> 4 consecutive channels).
__global__ __launch_bounds__(256) void attn_epilogue_kernel(
    const float* __restrict__ part, const float* __restrict__ bo,
    const float* __restrict__ x, const float* __restrict__ n2w,
    const float* __restrict__ wr, const float* __restrict__ br,
    float* __restrict__ x1, float* __restrict__ h2, int* __restrict__ top_i,
    float* __restrict__ top_p, float* __restrict__ probs_out) {
  int t = blockIdx.x;
  int tid = threadIdx.x;
  int c = tid * 4;
  // WO reduce (4 slices) + bias + residual
  float4 s = *(const float4*)(part + (size_t)t * CD + c);
#pragma unroll
  for (int z = 1; z < 4; ++z) {
    float4 p = *(const float4*)(part + ((size_t)z * CT + t) * CD + c);
    s.x += p.x; s.y += p.y; s.z += p.z; s.w += p.w;
  }
  float4 bv = *(const float4*)(bo + c);
  float4 xv = *(const float4*)(x + (size_t)t * CD + c);
  s.x += bv.x + xv.x; s.y += bv.y + xv.y;
  s.z += bv.z + xv.z; s.w += bv.w + xv.w;
  *(float4*)(x1 + (size_t)t * CD + c) = s;
  // rmsnorm
  float ss = s.x*s.x + s.y*s.y + s.z*s.z + s.w*s.w;
  for (int off = 32; off > 0; off >>= 1) ss += __shfl_down(ss, off);
  __shared__ float red[4];
  __shared__ float s_scale;
  int lane = tid & 63, wid = tid >> 6;
  if (lane == 0) red[wid] = ss;
  __syncthreads();
  if (tid == 0) {
    float tot = red[0] + red[1] + red[2] + red[3];
    s_scale = rsqrtf(tot / (float)CD + CEPS);
  }
  __syncthreads();
  float sc = s_scale;
  float4 wv = *(const float4*)(n2w + c);
  float hv[4] = {s.x * sc * wv.x, s.y * sc * wv.y,
                 s.z * sc * wv.z, s.w * sc * wv.w};
  *(float4*)(h2 + (size_t)t * CD + c) =
      make_float4(hv[0], hv[1], hv[2], hv[3]);
  // router logits
  float a[CE] = {};
#pragma unroll
  for (int j = 0; j < 4; ++j) {
    const float* wrow = wr + (size_t)(c + j) * CE;
#pragma unroll
    for (int e = 0; e < CE; ++e) a[e] += hv[j] * wrow[e];
  }
  __shared__ float red8[256][CE];
#pragma unroll
  for (int e = 0; e < CE; ++e) red8[tid][e] = a[e];
  __syncthreads();
  for (int st = 128; st > 0; st >>= 1) {
    if (tid < st) {
#pragma unroll
      for (int e = 0; e < CE; ++e) red8[tid][e] += red8[tid + st][e];
    }
    __syncthreads();
  }
  if (tid == 0) {
    float probs[CE];
    float mx = -1e30f;
#pragma unroll
    for (int e = 0; e < CE; ++e) {
      probs[e] = red8[0][e] + br[e];
      mx = fmaxf(mx, probs[e]);
    }
    float sum = 0.f;
#pragma unroll
    for (int e = 0; e < CE; ++e) { probs[e] = __expf(probs[e] - mx); sum += probs[e]; }
    float inv = 1.0f / sum;
#pragma unroll
    for (int e = 0; e < CE; ++e) {
      probs[e] *= inv;
      probs_out[t * CE + e] = probs[e];
    }
    int i1 = 0;
#pragma unroll
    for (int e = 1; e < CE; ++e) if (probs[e] > probs[i1]) i1 = e;
    int i2 = (i1 == 0) ? 1 : 0;
#pragma unroll
    for (int e = 0; e < CE; ++e)
      if (e != i1 && probs[e] > probs[i2]) i2 = e;
    float p1 = probs[i1], p2 = probs[i2];
    float s12 = p1 + p2;
    top_i[t * 2 + 0] = i1;
    top_i[t * 2 + 1] = i2;
    top_p[t * 2 + 0] = p1 / s12;
    top_p[t * 2 + 1] = p2 / s12;
  }
}

// ---------------------------------------------------------------------------
// Fused attention v3 (flash-style online softmax), unchanged from round 11.
__global__ __launch_bounds__(256) void fused_attn_kernel(
    const float* __restrict__ qkv, short* __restrict__ ctxh,
    short* __restrict__ ctxl) {
  __shared__ float Qs[32][68];
  __shared__ float Ks[64 * 65];
  __shared__ float Vs[64][68];
  __shared__ float Pt[32][66];
  int qt = blockIdx.x, bh = blockIdx.y;
  int b = bh / CH, h = bh % CH;
  int qrow0 = qt * 32;
  int ktmax = (qrow0 + 31) >> 6;
  int tid = threadIdx.x;
  int cg = tid & 31, rg = tid >> 5;
  int r0 = rg * 4;

#pragma unroll
  for (int it = 0; it < 2; ++it) {
    int idx = it * 256 + tid;
    int r = idx >> 4, c4 = (idx & 15) * 4;
    *(float4*)&Qs[r][c4] = *(const float4*)(
        qkv + (size_t)(b * CS + qrow0 + r) * QKVP + h * CHD + c4);
  }

  float m_i[4], l_i[4], O[4][2];
#pragma unroll
  for (int i = 0; i < 4; ++i) {
    m_i[i] = -1e30f;
    l_i[i] = 0.f;
    O[i][0] = 0.f;
    O[i][1] = 0.f;
  }

  for (int kt = 0; kt <= ktmax; ++kt) {
    __syncthreads();
#pragma unroll
    for (int it = 0; it < 4; ++it) {
      int idx = it * 256 + tid;
      int r = idx >> 4, c4 = (idx & 15) * 4;
      const float* src =
          qkv + (size_t)(b * CS + kt * 64 + r) * QKVP + h * CHD;
      float4 kv = *(const float4*)(src + 1024 + c4);
      Ks[r * 65 + c4 + 0] = kv.x;
      Ks[r * 65 + c4 + 1] = kv.y;
      Ks[r * 65 + c4 + 2] = kv.z;
      Ks[r * 65 + c4 + 3] = kv.w;
      *(float4*)&Vs[r][c4] = *(const float4*)(src + 2048 + c4);
    }
    __syncthreads();

    float s[4][2] = {};
#pragma unroll 4
    for (int d = 0; d < 64; ++d) {
      float q0 = Qs[r0 + 0][d];
      float q1 = Qs[r0 + 1][d];
      float q2 = Qs[r0 + 2][d];
      float q3 = Qs[r0 + 3][d];
      float k0 = Ks[(cg * 2 + 0) * 65 + d];
      float k1 = Ks[(cg * 2 + 1) * 65 + d];
      s[0][0] += q0 * k0; s[0][1] += q0 * k1;
      s[1][0] += q1 * k0; s[1][1] += q1 * k1;
      s[2][0] += q2 * k0; s[2][1] += q2 * k1;
      s[3][0] += q3 * k0; s[3][1] += q3 * k1;
    }

#pragma unroll
    for (int i = 0; i < 4; ++i) {
      int gr = qrow0 + r0 + i;
      int gc0 = kt * 64 + cg * 2;
      float s0 = (gc0 + 0 > gr) ? -1e30f : s[i][0] * 0.125f;
      float s1 = (gc0 + 1 > gr) ? -1e30f : s[i][1] * 0.125f;
      float tmax = fmaxf(s0, s1);
#pragma unroll
      for (int off = 16; off > 0; off >>= 1)
        tmax = fmaxf(tmax, __shfl_xor(tmax, off));
      float newm = fmaxf(m_i[i], tmax);
      float p0 = __expf(s0 - newm);
      float p1 = __expf(s1 - newm);
      float tsum = p0 + p1;
#pragma unroll
      for (int off = 16; off > 0; off >>= 1) tsum += __shfl_xor(tsum, off);
      float scale = __expf(m_i[i] - newm);
      l_i[i] = l_i[i] * scale + tsum;
      m_i[i] = newm;
      O[i][0] *= scale;
      O[i][1] *= scale;
      Pt[r0 + i][cg * 2 + 0] = p0;
      Pt[r0 + i][cg * 2 + 1] = p1;
    }
    __syncthreads();

#pragma unroll 4
    for (int c = 0; c < 64; ++c) {
      float p0 = Pt[r0 + 0][c];
      float p1 = Pt[r0 + 1][c];
      float p2 = Pt[r0 + 2][c];
      float p3 = Pt[r0 + 3][c];
      float v0 = Vs[c][cg];
      float v1 = Vs[c][cg + 32];
      O[0][0] += p0 * v0; O[0][1] += p0 * v1;
      O[1][0] += p1 * v0; O[1][1] += p1 * v1;
      O[2][0] += p2 * v0; O[2][1] += p2 * v1;
      O[3][0] += p3 * v0; O[3][1] += p3 * v1;
    }
  }

#pragma unroll
  for (int i = 0; i < 4; ++i) {
    float inv = 1.0f / l_i[i];
#pragma unroll
    for (int jd = 0; jd < 2; ++jd) {
      int dv = cg + 32 * jd;
      size_t oi = (size_t)(b * CS + qrow0 + r0 + i) * CD + h * CHD + dv;
      float v = O[i][jd] * inv;
      short hi = f2bf(v);
      ctxh[oi] = hi;
      ctxl[oi] = f2bf(v - bf2f(hi));
    }
  }
}

// ---------------------------------------------------------------------------
// Finalize (1 block): counts/psum, offsets, tile map, aux loss, cursor clear.
__global__ __launch_bounds__(256) void finalize_kernel(
    const int* __restrict__ top_i, const float* __restrict__ probs,
    int* __restrict__ offs, int* __restrict__ tile_e,
    int* __restrict__ total_padded, int* __restrict__ row_map,
    int* __restrict__ cursor, float* __restrict__ aux_out) {
  int tid = threadIdx.x;
  __shared__ float redp[256][CE];
  __shared__ int redc[256][CE];
  float lp[CE] = {};
  int lc[CE] = {};
  for (int t = tid; t < CT; t += 256) {
    lc[top_i[t * 2 + 0]]++;
    lc[top_i[t * 2 + 1]]++;
#pragma unroll
    for (int e = 0; e < CE; ++e) lp[e] += probs[t * CE + e];
  }
#pragma unroll
  for (int e = 0; e < CE; ++e) { redp[tid][e] = lp[e]; redc[tid][e] = lc[e]; }
  __syncthreads();
  for (int s = 128; s > 0; s >>= 1) {
    if (tid < s) {
#pragma unroll
      for (int e = 0; e < CE; ++e) {
        redp[tid][e] += redp[tid + s][e];
        redc[tid][e] += redc[tid + s][e];
      }
    }
    __syncthreads();
  }
  __shared__ int s_off[CE + 1];
  if (tid == 0) {
    int o = 0;
    for (int e = 0; e < CE; ++e) {
      s_off[e] = o;
      offs[e] = o;
      o += ((redc[0][e] + 127) >> 7) << 7;
    }
    s_off[CE] = o;
    offs[CE] = o;
    *total_padded = o;
    int nt = o >> 7;
    for (int i = 0; i < nt; ++i) {
      int e = 0;
      while (e < CE - 1 && i * 128 >= s_off[e + 1]) e++;
      tile_e[i] = e;
    }
    float aux = 0.f;
    for (int e = 0; e < CE; ++e)
      aux += ((float)redc[0][e] / (float)(CT * CK)) * (redp[0][e] / (float)CT);
    aux_out[0] = aux * (float)CE;
  }
  if (tid < CE) cursor[tid] = 0;
  __syncthreads();
  for (int i = tid; i < MAXROWS; i += blockDim.x) row_map[i] = -1;
}

__global__ void gather_kernel(const int* __restrict__ top_i,
                              const int* __restrict__ offs,
                              int* __restrict__ cursor, int* __restrict__ row_map,
                              int* __restrict__ row_of) {
  int idx = blockIdx.x * blockDim.x + threadIdx.x;
  if (idx >= CT * CK) return;
  int e = top_i[idx];
  int pos = offs[e] + atomicAdd(&cursor[e], 1);
  row_map[pos] = idx >> 1;
  row_of[idx] = pos;
}

// Xg[row] = bf16(h2[row_map[row]]) or zeros for pad rows.
__global__ __launch_bounds__(256) void gatherx_kernel(
    const float* __restrict__ h2, const int* __restrict__ row_map,
    short* __restrict__ Xg) {
  int row = blockIdx.x;
  int tid = threadIdx.x;
  int tok = row_map[row];
  short4 o;
  if (tok < 0) {
    o = make_short4(0, 0, 0, 0);
  } else {
    float4 v = ((const float4*)(h2 + (size_t)tok * CD))[tid];
    o = make_short4(f2bf(v.x), f2bf(v.y), f2bf(v.z), f2bf(v.w));
  }
  ((short4*)(Xg + (size_t)row * CD))[tid] = o;
}

// Fused GEMM2-reduce + combine: per token, read only its 2 routed rows'
// partials, add b2[e], weight, residual. out[t] = x1[t] + sum_s w_s*ff_row_s.
__global__ __launch_bounds__(256) void combine_g2_kernel(
    const float* __restrict__ part, int partM, int nz,
    const float* __restrict__ b2, const int* __restrict__ tile_e,
    const int* __restrict__ row_of, const float* __restrict__ top_p,
    const float* __restrict__ x1, float* __restrict__ out) {
  int t = blockIdx.x;
  int c = threadIdx.x * 4;
  float4 r = *(const float4*)(x1 + (size_t)t * CD + c);
#pragma unroll
  for (int s = 0; s < CK; ++s) {
    int row = row_of[t * 2 + s];
    int e = tile_e[row >> 7];
    float w = top_p[t * 2 + s];
    float4 acc = *(const float4*)(part + (size_t)row * CD + c);
    for (int z = 1; z < nz; ++z) {
      float4 p = *(const float4*)(part + ((size_t)z * partM + row) * CD + c);
      acc.x += p.x; acc.y += p.y; acc.z += p.z; acc.w += p.w;
    }
    float4 bv = *(const float4*)(b2 + (size_t)e * CD + c);
    r.x += w * (acc.x + bv.x);
    r.y += w * (acc.y + bv.y);
    r.z += w * (acc.z + bv.z);
    r.w += w * (acc.w + bv.w);
  }
  *(float4*)(out + (size_t)t * CD + c) = r;
}

// ---------------------------------------------------------------------------
extern "C" void kernel_launch(void* const* d_in, const int* in_sizes, int n_in,
                              void* d_out, int out_size, void* d_ws,
                              size_t ws_size, hipStream_t stream) {
  const float* x   = (const float*)d_in[0];
  const float* n1w = (const float*)d_in[1];
  const float* n2w = (const float*)d_in[2];
  const float* wq  = (const float*)d_in[3];
  const float* bq  = (const float*)d_in[4];
  const float* wk  = (const float*)d_in[5];
  const float* bk  = (const float*)d_in[6];
  const float* wv  = (const float*)d_in[7];
  const float* bv  = (const float*)d_in[8];
  const float* wo  = (const float*)d_in[9];
  const float* bo  = (const float*)d_in[10];
  const float* wr  = (const float*)d_in[11];
  const float* br  = (const float*)d_in[12];
  const float* w1  = (const float*)d_in[13];
  const float* b1  = (const float*)d_in[14];
  const float* w2  = (const float*)d_in[15];
  const float* b2  = (const float*)d_in[16];
  float* out = (float*)d_out;

  char* base = (char*)d_ws;
  size_t off = 0;
  auto alloc = [&](size_t bytes) -> void* {
    void* p = base + off;
    off += (bytes + 255) & ~(size_t)255;
    return p;
  };
  float* f_x1   = (float*)alloc((size_t)CT * CD * 4);
  float* f_h2   = (float*)alloc((size_t)CT * CD * 4);
  short* f_xg   = (short*)alloc((size_t)MAXROWS * CD * 2);
  short* f_hid  = (short*)alloc((size_t)MAXROWS * CF * 2);
  short* f_hh   = (short*)alloc((size_t)CT * CD * 2);
  short* f_hl   = (short*)alloc((size_t)CT * CD * 2);
  short* f_wqkvh = (short*)alloc((size_t)QKVP * CD * 2);
  short* f_wqkvl = (short*)alloc((size_t)QKVP * CD * 2);
  float* f_qkv  = (float*)alloc((size_t)CT * QKVP * 4);
  short* f_ctxh = (short*)alloc((size_t)CT * CD * 2);
  short* f_ctxl = (short*)alloc((size_t)CT * CD * 2);
  short* f_woth = (short*)alloc((size_t)CD * CD * 2);
  short* f_wotl = (short*)alloc((size_t)CD * CD * 2);
  float* f_bqkv = (float*)alloc(QKVP * 4);
  float* f_topp = (float*)alloc(CT * CK * 4);
  float* f_probs = (float*)alloc(CT * CE * 4);
  int* i_topi   = (int*)alloc(CT * CK * 4);
  int* i_rowof  = (int*)alloc(CT * CK * 4);
  int* i_rowmap = (int*)alloc(MAXROWS * 4);
  int* i_cursor = (int*)alloc(CE * 4);
  int* i_offs   = (int*)alloc((CE + 1) * 4);
  int* i_tile   = (int*)alloc(MAXTILES * 4);
  int* i_total  = (int*)alloc(4);
  // G (64MB): w1t -> w2t (sequential reuse)
  short* f_wG = (short*)alloc((size_t)CE * CD * CF * 2);
  short* f_w1t = f_wG;
  short* f_w2t = f_wG;
  // Rs (48MB): QKV partials -> WO partials -> GEMM2 partials (disjoint)
  void* Rs = alloc((size_t)4 * MAXROWS * CD * 4);
  float* f_partqkv = (float*)Rs;
  float* f_partwo = (float*)Rs;
  float* f_partg2 = (float*)Rs;

  dim3 b256(256);

  pack_bias_kernel<<<QKVP / 256, b256, 0, stream>>>(bq, bk, bv, f_bqkv);
  // wq/wk/wv/wo transposes in one launch (hi/lo planes)
  TPtrs tp;
  tp.w[0] = wq; tp.w[1] = wk; tp.w[2] = wv; tp.w[3] = wo;
  tp.hh[0] = f_wqkvh + 0 * (size_t)CD * CD;
  tp.hh[1] = f_wqkvh + 1 * (size_t)CD * CD;
  tp.hh[2] = f_wqkvh + 2 * (size_t)CD * CD;
  tp.hh[3] = f_woth;
  tp.ll[0] = f_wqkvl + 0 * (size_t)CD * CD;
  tp.ll[1] = f_wqkvl + 1 * (size_t)CD * CD;
  tp.ll[2] = f_wqkvl + 2 * (size_t)CD * CD;
  tp.ll[3] = f_wotl;
  transpose4_kernel<<<dim3(16, 16, 4), b256, 0, stream>>>(tp);
  transpose_convert_kernel<<<dim3(CF / 64, CD / 64, CE), b256, 0, stream>>>(
      w1, f_w1t, nullptr, CD, CF);

  // ---- attention ----
  rmsnorm_hl_kernel<<<CT, b256, 0, stream>>>(x, n1w, f_hh, f_hl);
  mfma_gemm_kernel<1><<<dim3(QKVP / 128, CT / 128, 2), b256, 0, stream>>>(
      f_hh, f_hl, f_wqkvh, f_wqkvl, f_partqkv, CT, QKVP, CD);
  reduce_splitk_kernel<<<CT, b256, 0, stream>>>(f_partqkv, CT, 2, f_bqkv,
                                                f_qkv, QKVP);
  fused_attn_kernel<<<dim3(CS / 32, CBH), b256, 0, stream>>>(f_qkv, f_ctxh,
                                                             f_ctxl);
  mfma_gemm_kernel<1><<<dim3(CD / 128, CT / 128, 4), b256, 0, stream>>>(
      f_ctxh, f_ctxl, f_woth, f_wotl, f_partwo, CT, CD, CD);
  // fused: WO reduce + residual + rmsnorm2 + router
  attn_epilogue_kernel<<<CT, b256, 0, stream>>>(f_partwo, bo, x, n2w, wr, br,
                                                f_x1, f_h2, i_topi, f_topp,
                                                f_probs);

  // ---- MoE ----
  finalize_kernel<<<1, 256, 0, stream>>>(i_topi, f_probs, i_offs, i_tile,
                                         i_total, i_rowmap, i_cursor,
                                         out + (size_t)CT * CD);
  gather_kernel<<<(CT * CK + 255) / 256, b256, 0, stream>>>(i_topi, i_offs,
                                                            i_cursor, i_rowmap,
                                                            i_rowof);
  gatherx_kernel<<<MAXROWS, b256, 0, stream>>>(f_h2, i_rowmap, f_xg);

  moe_gemm_kernel<1, 1><<<dim3(CF / 256, MAXTILES, 1), dim3(512), 0, stream>>>(
      f_xg, f_w1t, b1, f_hid, nullptr, 0, CF, CD, i_tile, i_total);
  transpose_convert_kernel<<<dim3(CD / 64, CF / 64, CE), b256, 0, stream>>>(
      w2, f_w2t, nullptr, CF, CD);
  moe_gemm_kernel<0, 0><<<dim3(CD / 256, MAXTILES, 4), dim3(512), 0, stream>>>(
      f_hid, f_w2t, nullptr, nullptr, f_partg2, MAXROWS, CD, CF, i_tile,
      i_total);
  // fused: GEMM2 reduce + combine (+x1 residual)
  combine_g2_kernel<<<CT, b256, 0, stream>>>(f_partg2, MAXROWS, 4, b2, i_tile,
                                             i_rowof, f_topp, f_x1, out);
}